// Round 13
// baseline (62.631 us; speedup 1.0000x reference)
//
#include <hip/hip_runtime.h>

#define TWO_LOG2E 2.8853900817779268f

__device__ __forceinline__ float frcp(float x) {
#if __has_builtin(__builtin_amdgcn_rcpf)
  return __builtin_amdgcn_rcpf(x);
#else
  return 1.0f / x;
#endif
}
__device__ __forceinline__ float fexp2(float x) {
#if __has_builtin(__builtin_amdgcn_exp2f)
  return __builtin_amdgcn_exp2f(x);
#else
  return exp2f(x);
#endif
}
__device__ __forceinline__ unsigned short f2bf(float f) {  // RNE f32->bf16
  unsigned int u = __float_as_uint(f);
  u += 0x7fffu + ((u >> 16) & 1u);
  return (unsigned short)(u >> 16);
}
__device__ __forceinline__ unsigned int pack2bf(float lo, float hi) {
  return (unsigned int)f2bf(lo) | ((unsigned int)f2bf(hi) << 16);
}

using short8 = __attribute__((ext_vector_type(8))) short;
using f32x4v = __attribute__((ext_vector_type(4))) float;
using f32x4s = __attribute__((ext_vector_type(4))) float;
using f32x2 = __attribute__((ext_vector_type(2))) float;

__device__ __forceinline__ f32x2 pkfma(f32x2 a, f32x2 b, f32x2 c) {
  return __builtin_elementwise_fma(a, b, c);
}
__device__ __forceinline__ f32x2 splat2(float x) {
  f32x2 r;
  r.x = x;
  r.y = x;
  return r;
}
__device__ __forceinline__ f32x2 unpack_bf2(unsigned u) {  // (k-even, k-odd)
  f32x2 r;
  r.x = __uint_as_float(u << 16);
  r.y = __uint_as_float(u & 0xffff0000u);
  return r;
}
// s += sum_{i=0..3} v_i/(a_i*b_i+1) for BOTH k-parities, ONE rcp per parity.
__device__ __forceinline__ void cell4k(float a0, float a1, float a2, float a3,
                                       f32x2 b0, f32x2 b1, f32x2 b2, f32x2 b3,
                                       float v0, float v1, float v2, float v3,
                                       f32x2& s) {
  const f32x2 one = {1.f, 1.f};
  f32x2 x0 = pkfma(splat2(a0), b0, one);
  f32x2 x1 = pkfma(splat2(a1), b1, one);
  f32x2 x2 = pkfma(splat2(a2), b2, one);
  f32x2 x3 = pkfma(splat2(a3), b3, one);
  f32x2 p01 = x0 * x1, p23 = x2 * x3;
  f32x2 n01 = pkfma(splat2(v0), x1, splat2(v1) * x0);
  f32x2 n23 = pkfma(splat2(v2), x3, splat2(v3) * x2);
  f32x2 num = pkfma(n01, p23, n23 * p01);
  f32x2 den = p01 * p23;
  f32x2 r;
  r.x = frcp(den.x);
  r.y = frcp(den.y);
  s = pkfma(num, r, s);
}

// ---------------------------------------------------------------------------
// k_pre: fused projections + value transpose (unchanged from r12).
// ---------------------------------------------------------------------------
__global__ __launch_bounds__(256) void k_pre(
    const float* __restrict__ query, const float* __restrict__ key,
    const float* __restrict__ w1, const float* __restrict__ w2,
    const float* __restrict__ value,
    float* __restrict__ Aout, unsigned short* __restrict__ BoutT,
    unsigned short* __restrict__ valT) {
  __shared__ __align__(16) char Abuf[16 * 128];   // [m][k] bf16, swizzled
  __shared__ __align__(16) char Bbuf[128 * 128];  // [n][k] bf16, swizzled
  __shared__ unsigned short ts[64][66];           // valT transpose buffer

  const int t = threadIdx.x;

  if (blockIdx.y == 0) {  // ---- projections ----
    const int px = blockIdx.x;
    const bool isB = px >= 256;
    const float* in = isB ? key : query;
    const float* wm = isB ? w2 : w1;
    const int m0g = (px & 255) * 16;
    const int w = t >> 6, l = t & 63;

    f32x4v acc[2];
    acc[0] = 0;
    acc[1] = 0;

    float4 aS;
    float4 wS[4][2];

#define P_LOAD(k0_)                                                        \
  {                                                                        \
    aS = *(const float4*)&in[(m0g + (t >> 4)) * 512 + (k0_) + (t & 15) * 4]; \
    _Pragma("unroll") for (int i = 0; i < 4; ++i) {                        \
      int tt = t + i * 256;                                                \
      int row = tt >> 3, g = tt & 7;                                       \
      const float* src = &wm[row * 512 + (k0_) + g * 8];                   \
      wS[i][0] = *(const float4*)src;                                      \
      wS[i][1] = *(const float4*)(src + 4);                                \
    }                                                                      \
  }
#define P_WRITE()                                                          \
  {                                                                        \
    int arow = t >> 4, q4 = t & 15;                                        \
    *(uint2*)(Abuf + arow * 128 + (((q4 >> 1) ^ (arow & 7)) << 4) +        \
              ((q4 & 1) << 3)) =                                           \
        make_uint2(pack2bf(aS.x, aS.y), pack2bf(aS.z, aS.w));              \
    _Pragma("unroll") for (int i = 0; i < 4; ++i) {                        \
      int tt = t + i * 256;                                                \
      int row = tt >> 3, g = tt & 7;                                       \
      uint4 p = make_uint4(                                                \
          pack2bf(wS[i][0].x, wS[i][0].y), pack2bf(wS[i][0].z, wS[i][0].w),\
          pack2bf(wS[i][1].x, wS[i][1].y), pack2bf(wS[i][1].z, wS[i][1].w));\
      *(uint4*)(Bbuf + row * 128 + ((g ^ (row & 7)) << 4)) = p;            \
    }                                                                      \
  }

    P_LOAD(0);
#pragma unroll
    for (int ks8 = 0; ks8 < 8; ++ks8) {
      if (ks8) __syncthreads();
      P_WRITE();
      if (ks8 < 7) P_LOAD(ks8 * 64 + 64);
      __syncthreads();
#pragma unroll
      for (int ks = 0; ks < 2; ++ks) {
        const int gb = ks * 4 + (l >> 4);
        const int ra = l & 15;
        short8 af = *(const short8*)(Abuf + ra * 128 + ((gb ^ (ra & 7)) << 4));
#pragma unroll
        for (int ni = 0; ni < 2; ++ni) {
          const int rb = w * 32 + ni * 16 + (l & 15);
          short8 bf_ = *(const short8*)(Bbuf + rb * 128 + ((gb ^ (rb & 7)) << 4));
          if (isB)
            acc[ni] = __builtin_amdgcn_mfma_f32_16x16x32_bf16(bf_, af, acc[ni], 0, 0, 0);
          else
            acc[ni] = __builtin_amdgcn_mfma_f32_16x16x32_bf16(af, bf_, acc[ni], 0, 0, 0);
        }
      }
    }
#undef P_LOAD
#undef P_WRITE
    if (!isB) {
#pragma unroll
      for (int ni = 0; ni < 2; ++ni) {
        int col = w * 32 + ni * 16 + (l & 15);  // h
#pragma unroll
        for (int j = 0; j < 4; ++j) {
          int row = m0g + (l >> 4) * 4 + j;  // m
          Aout[row * 128 + col] = fexp2(acc[ni][j] * TWO_LOG2E);
        }
      }
    } else {
      int m = m0g + (l & 15);  // contiguous across lanes
#pragma unroll
      for (int ni = 0; ni < 2; ++ni)
#pragma unroll
        for (int j = 0; j < 4; ++j) {
          int h = w * 32 + ni * 16 + (l >> 4) * 4 + j;
          BoutT[h * 4096 + m] = f2bf(fexp2(acc[ni][j] * TWO_LOG2E));
        }
    }
  } else {  // ---- valT ----
    const int x = blockIdx.x;
    const int b = x >> 6, k0 = ((x >> 3) & 7) * 64, n0 = (x & 7) * 64;
    {
      int kr = t >> 4, n4 = (t & 15) * 4;
#pragma unroll
      for (int i = 0; i < 4; ++i) {
        float4 f =
            *(const float4*)&value[((b * 512) + k0 + kr + 16 * i) * 512 + n0 + n4];
        *(ushort4*)&ts[kr + 16 * i][n4] =
            make_ushort4(f2bf(f.x), f2bf(f.y), f2bf(f.z), f2bf(f.w));
      }
    }
    __syncthreads();
    {
      int nw = t >> 4, k4 = (t & 15) * 4;
#pragma unroll
      for (int i = 0; i < 4; ++i) {
        int n = nw + 16 * i;
        ushort4 o = make_ushort4(ts[k4 + 0][n], ts[k4 + 1][n], ts[k4 + 2][n],
                                 ts[k4 + 3][n]);
        *(ushort4*)&valT[((b * 512) + n0 + n) * 512 + k0 + k4] = o;
      }
    }
  }
}

// ---------------------------------------------------------------------------
// K2: S[q,k] = sum_h v[h]/(A[q,h]*B[k,h]+1);  attn = softmax_k(-2S).
// 4 q-rows/block. Software-pipelined: per 4-h chunk, SMEM (A rows + v, via
// s_load_dwordx4 + imm offsets) AND B dwords are prefetched ONE CHUNK AHEAD
// into alternate buffers; lgkmcnt(0) at step start sees only the prefetched
// chunk (SMEM is OoO so only wait-0 is safe; two-buffer wait-before-use).
// No min-pass: |S| <= sum|v| ~ 9, exp(-2S) <= e^22, softmax shift-invariant.
// grid (128,8) = 4 blocks/CU, block 256 (waves = k-quarters).
// ---------------------------------------------------------------------------
__global__ __launch_bounds__(256, 4) void k_score_softmax(
    const float* __restrict__ Aexp, const unsigned short* __restrict__ BexpT,
    const float* __restrict__ vw, float* __restrict__ attn) {
  __shared__ float red[4][4];

  const int tid = threadIdx.x;
  const int b = blockIdx.y;
  const int qbase = blockIdx.x * 4;
  const int wav = tid >> 6;   // k-quarter
  const int lane = tid & 63;

  const unsigned* const bbase32 = (const unsigned*)(BexpT + b * 512);
  const int kidx = wav * 64 + lane;  // dword index within a k-row

  const float* const pa0 =
      Aexp + __builtin_amdgcn_readfirstlane((b * 512 + qbase) * 128);
  const float* const pv = vw;

  f32x2 acc0 = {0.f, 0.f}, acc1 = {0.f, 0.f};
  f32x2 acc2 = {0.f, 0.f}, acc3 = {0.f, 0.f};

  f32x4s A0a, A1a, A2a, A3a, Va, A0b, A1b, A2b, A3b, Vb;
  unsigned ua[4], ub[4];

// Issue SMEM loads for chunk at byte-offset COFF into one buffer set.
// Rows are +512B apart (128 floats); imm21 offsets, no soffset SGPR.
#define K2_SMEM(S0_, S1_, S2_, S3_, SV_, COFF_)                            \
  asm volatile(                                                            \
      "s_load_dwordx4 %0, %5, %7\n\t"                                      \
      "s_load_dwordx4 %1, %5, %8\n\t"                                      \
      "s_load_dwordx4 %2, %5, %9\n\t"                                      \
      "s_load_dwordx4 %3, %5, %10\n\t"                                     \
      "s_load_dwordx4 %4, %6, %7"                                          \
      : "=&s"(S0_), "=&s"(S1_), "=&s"(S2_), "=&s"(S3_), "=&s"(SV_)         \
      : "s"(pa0), "s"(pv), "i"(COFF_), "i"((COFF_) + 512),                 \
        "i"((COFF_) + 1024), "i"((COFF_) + 1536))

#define K2_BLD(U_, c_)                                                     \
  {                                                                        \
    _Pragma("unroll") for (int j = 0; j < 4; ++j)                          \
        U_[j] = bbase32[((c_) * 4 + j) * 2048 + kidx];                     \
  }

// One step: wait for cur SMEM, prefetch next (SMEM + B), compute cur.
#define K2_STEP(c_, S0_, S1_, S2_, S3_, SV_, N0_, N1_, N2_, N3_, NV_,      \
                UC_, UN_, LAST_)                                           \
  {                                                                        \
    asm volatile("s_waitcnt lgkmcnt(0)"                                    \
                 : "+s"(S0_), "+s"(S1_), "+s"(S2_), "+s"(S3_), "+s"(SV_)); \
    if (!(LAST_)) {                                                        \
      K2_SMEM(N0_, N1_, N2_, N3_, NV_, ((c_) + 1) * 16);                   \
      K2_BLD(UN_, (c_) + 1);                                               \
    }                                                                      \
    f32x2 b0 = unpack_bf2(UC_[0]);                                         \
    f32x2 b1 = unpack_bf2(UC_[1]);                                         \
    f32x2 b2 = unpack_bf2(UC_[2]);                                         \
    f32x2 b3 = unpack_bf2(UC_[3]);                                         \
    cell4k(S0_[0], S0_[1], S0_[2], S0_[3], b0, b1, b2, b3,                 \
           SV_[0], SV_[1], SV_[2], SV_[3], acc0);                          \
    cell4k(S1_[0], S1_[1], S1_[2], S1_[3], b0, b1, b2, b3,                 \
           SV_[0], SV_[1], SV_[2], SV_[3], acc1);                          \
    cell4k(S2_[0], S2_[1], S2_[2], S2_[3], b0, b1, b2, b3,                 \
           SV_[0], SV_[1], SV_[2], SV_[3], acc2);                          \
    cell4k(S3_[0], S3_[1], S3_[2], S3_[3], b0, b1, b2, b3,                 \
           SV_[0], SV_[1], SV_[2], SV_[3], acc3);                          \
  }

#define K2_STEP_AB(c_, LAST_)                                              \
  K2_STEP(c_, A0a, A1a, A2a, A3a, Va, A0b, A1b, A2b, A3b, Vb, ua, ub, LAST_)
#define K2_STEP_BA(c_, LAST_)                                              \
  K2_STEP(c_, A0b, A1b, A2b, A3b, Vb, A0a, A1a, A2a, A3a, Va, ub, ua, LAST_)

  K2_SMEM(A0a, A1a, A2a, A3a, Va, 0);
  K2_BLD(ua, 0);
  K2_STEP_AB(0, false)
  K2_STEP_BA(1, false)
  K2_STEP_AB(2, false)
  K2_STEP_BA(3, false)
  K2_STEP_AB(4, false)
  K2_STEP_BA(5, false)
  K2_STEP_AB(6, false)
  K2_STEP_BA(7, false)
  K2_STEP_AB(8, false)
  K2_STEP_BA(9, false)
  K2_STEP_AB(10, false)
  K2_STEP_BA(11, false)
  K2_STEP_AB(12, false)
  K2_STEP_BA(13, false)
  K2_STEP_AB(14, false)
  K2_STEP_BA(15, false)
  K2_STEP_AB(16, false)
  K2_STEP_BA(17, false)
  K2_STEP_AB(18, false)
  K2_STEP_BA(19, false)
  K2_STEP_AB(20, false)
  K2_STEP_BA(21, false)
  K2_STEP_AB(22, false)
  K2_STEP_BA(23, false)
  K2_STEP_AB(24, false)
  K2_STEP_BA(25, false)
  K2_STEP_AB(26, false)
  K2_STEP_BA(27, false)
  K2_STEP_AB(28, false)
  K2_STEP_BA(29, false)
  K2_STEP_AB(30, false)
  K2_STEP_BA(31, true)
#undef K2_SMEM
#undef K2_BLD
#undef K2_STEP
#undef K2_STEP_AB
#undef K2_STEP_BA

  // attn = exp(-2S)/sum (no max-subtraction: |S|<=sum|v|~9, e^22 safe).
  float P0e = fexp2(acc0.x * -TWO_LOG2E);
  float P0o = fexp2(acc0.y * -TWO_LOG2E);
  float P1e = fexp2(acc1.x * -TWO_LOG2E);
  float P1o = fexp2(acc1.y * -TWO_LOG2E);
  float P2e = fexp2(acc2.x * -TWO_LOG2E);
  float P2o = fexp2(acc2.y * -TWO_LOG2E);
  float P3e = fexp2(acc3.x * -TWO_LOG2E);
  float P3o = fexp2(acc3.y * -TWO_LOG2E);
  float s0 = P0e + P0o, s1 = P1e + P1o, s2 = P2e + P2o, s3 = P3e + P3o;
#pragma unroll
  for (int off = 32; off > 0; off >>= 1) {
    s0 += __shfl_xor(s0, off);
    s1 += __shfl_xor(s1, off);
    s2 += __shfl_xor(s2, off);
    s3 += __shfl_xor(s3, off);
  }
  if (lane == 0) {
    red[wav][0] = s0; red[wav][1] = s1; red[wav][2] = s2; red[wav][3] = s3;
  }
  __syncthreads();
  float r0 = frcp(red[0][0] + red[1][0] + red[2][0] + red[3][0]);
  float r1 = frcp(red[0][1] + red[1][1] + red[2][1] + red[3][1]);
  float r2 = frcp(red[0][2] + red[1][2] + red[2][2] + red[3][2]);
  float r3 = frcp(red[0][3] + red[1][3] + red[2][3] + red[3][3]);

  const int row0 = (b * 512 + qbase) * 512;
  const int k0 = kidx * 2;
  *(float2*)&attn[row0 + k0] = make_float2(P0e * r0, P0o * r0);
  *(float2*)&attn[row0 + 512 + k0] = make_float2(P1e * r1, P1o * r1);
  *(float2*)&attn[row0 + 1024 + k0] = make_float2(P2e * r2, P2o * r2);
  *(float2*)&attn[row0 + 1536 + k0] = make_float2(P3e * r3, P3o * r3);
}

// ---------------------------------------------------------------------------
// K3: context[b] = attn[b] @ value[b] via bf16 MFMA 16x16x32 (unchanged).
// ---------------------------------------------------------------------------
__global__ __launch_bounds__(256) void k_context_mfma(
    const float* __restrict__ attn, const unsigned short* __restrict__ valT,
    float* __restrict__ ctx) {
  __shared__ __align__(16) char At[64 * 128];
  __shared__ __align__(16) char Bt[64 * 128];

  const int t = threadIdx.x;
  const int b = blockIdx.z;
  const int m0 = blockIdx.y * 64, n0 = blockIdx.x * 64;
  const int w = t >> 6, l = t & 63;
  const int wr = w >> 1, wc = w & 1;

  f32x4v acc[2][2];
  acc[0][0] = 0; acc[0][1] = 0; acc[1][0] = 0; acc[1][1] = 0;

  const int sr = t >> 2;
  const int sg = (t & 3);
  const int sswz = sr & 7;

  for (int k0 = 0; k0 < 512; k0 += 64) {
    if (k0) __syncthreads();
    {
      const float* src = &attn[(b * 512 + m0 + sr) * 512 + k0 + sg * 16];
      char* dst = At + sr * 128;
#pragma unroll
      for (int h = 0; h < 2; ++h) {
        float4 f0 = *(const float4*)(src + h * 8);
        float4 f1 = *(const float4*)(src + h * 8 + 4);
        uint4 p = make_uint4(pack2bf(f0.x, f0.y), pack2bf(f0.z, f0.w),
                             pack2bf(f1.x, f1.y), pack2bf(f1.z, f1.w));
        int g = sg * 2 + h;
        *(uint4*)(dst + ((g ^ sswz) << 4)) = p;
      }
      const unsigned short* srcb = &valT[(b * 512 + n0 + sr) * 512 + k0];
      char* dstb = Bt + sr * 128;
#pragma unroll
      for (int h = 0; h < 2; ++h) {
        int g = sg + h * 4;
        uint4 vb = *(const uint4*)(srcb + g * 8);
        *(uint4*)(dstb + ((g ^ sswz) << 4)) = vb;
      }
    }
    __syncthreads();
#pragma unroll
    for (int ks = 0; ks < 2; ++ks) {
      const int gb = ks * 4 + (l >> 4);
      short8 af[2], bf_[2];
#pragma unroll
      for (int mi = 0; mi < 2; ++mi) {
        int ra = wr * 32 + mi * 16 + (l & 15);
        af[mi] = *(const short8*)(At + ra * 128 + ((gb ^ (ra & 7)) << 4));
      }
#pragma unroll
      for (int ni = 0; ni < 2; ++ni) {
        int rb = wc * 32 + ni * 16 + (l & 15);
        bf_[ni] = *(const short8*)(Bt + rb * 128 + ((gb ^ (rb & 7)) << 4));
      }
#pragma unroll
      for (int mi = 0; mi < 2; ++mi)
#pragma unroll
        for (int ni = 0; ni < 2; ++ni)
          acc[mi][ni] = __builtin_amdgcn_mfma_f32_16x16x32_bf16(
              af[mi], bf_[ni], acc[mi][ni], 0, 0, 0);
    }
  }
  __syncthreads();
#pragma unroll
  for (int mi = 0; mi < 2; ++mi)
#pragma unroll
    for (int ni = 0; ni < 2; ++ni) {
      int col = n0 + wc * 32 + ni * 16 + (l & 15);
#pragma unroll
      for (int j = 0; j < 4; ++j) {
        int row = m0 + wr * 32 + mi * 16 + (l >> 4) * 4 + j;
        ctx[(b * 512 + row) * 512 + col] = acc[mi][ni][j];
      }
    }
}

extern "C" void kernel_launch(void* const* d_in, const int* in_sizes, int n_in,
                              void* d_out, int out_size, void* d_ws, size_t ws_size,
                              hipStream_t stream) {
  const float* query = (const float*)d_in[0];
  const float* key   = (const float*)d_in[1];
  const float* value = (const float*)d_in[2];
  const float* w1    = (const float*)d_in[3];
  const float* w2    = (const float*)d_in[4];
  const float* v     = (const float*)d_in[5];

  float* attn = (float*)d_out;
  float* ctx  = attn + 8 * 512 * 512;

  float* Aexp = (float*)d_ws;                                    // 4096*128 f32
  unsigned short* BexpT = (unsigned short*)(Aexp + 4096 * 128);  // 128*4096 bf16
  unsigned short* valT = BexpT + 128 * 4096;                     // 8*512*512 bf16

  k_pre<<<dim3(512, 2), 256, 0, stream>>>(query, key, w1, w2, value,
                                          Aexp, BexpT, valT);
  k_score_softmax<<<dim3(128, 8), 256, 0, stream>>>(Aexp, BexpT, v, attn);
  k_context_mfma<<<dim3(8, 8, 8), 256, 0, stream>>>(attn, valT, ctx);
}

// Round 15
// 60.346 us; speedup vs baseline: 1.0379x; 1.0379x over previous
//
#include <hip/hip_runtime.h>

#define TWO_LOG2E 2.8853900817779268f

__device__ __forceinline__ float frcp(float x) {
#if __has_builtin(__builtin_amdgcn_rcpf)
  return __builtin_amdgcn_rcpf(x);
#else
  return 1.0f / x;
#endif
}
__device__ __forceinline__ float fexp2(float x) {
#if __has_builtin(__builtin_amdgcn_exp2f)
  return __builtin_amdgcn_exp2f(x);
#else
  return exp2f(x);
#endif
}
__device__ __forceinline__ unsigned short f2bf(float f) {  // RNE f32->bf16
  unsigned int u = __float_as_uint(f);
  u += 0x7fffu + ((u >> 16) & 1u);
  return (unsigned short)(u >> 16);
}
__device__ __forceinline__ unsigned int pack2bf(float lo, float hi) {
  return (unsigned int)f2bf(lo) | ((unsigned int)f2bf(hi) << 16);
}

using short8 = __attribute__((ext_vector_type(8))) short;
using f32x4v = __attribute__((ext_vector_type(4))) float;
using f32x8s = __attribute__((ext_vector_type(8))) float;
using f32x2 = __attribute__((ext_vector_type(2))) float;

__device__ __forceinline__ f32x2 pkfma(f32x2 a, f32x2 b, f32x2 c) {
  return __builtin_elementwise_fma(a, b, c);
}
__device__ __forceinline__ f32x2 splat2(float x) {
  f32x2 r;
  r.x = x;
  r.y = x;
  return r;
}
__device__ __forceinline__ f32x2 unpack_bf2(unsigned u) {  // (k-even, k-odd)
  f32x2 r;
  r.x = __uint_as_float(u << 16);
  r.y = __uint_as_float(u & 0xffff0000u);
  return r;
}
// s += sum_{i=0..3} v_i/(a_i*b_i+1) for BOTH k-parities, ONE rcp per parity.
__device__ __forceinline__ void cell4k(float a0, float a1, float a2, float a3,
                                       f32x2 b0, f32x2 b1, f32x2 b2, f32x2 b3,
                                       float v0, float v1, float v2, float v3,
                                       f32x2& s) {
  const f32x2 one = {1.f, 1.f};
  f32x2 x0 = pkfma(splat2(a0), b0, one);
  f32x2 x1 = pkfma(splat2(a1), b1, one);
  f32x2 x2 = pkfma(splat2(a2), b2, one);
  f32x2 x3 = pkfma(splat2(a3), b3, one);
  f32x2 p01 = x0 * x1, p23 = x2 * x3;
  f32x2 n01 = pkfma(splat2(v0), x1, splat2(v1) * x0);
  f32x2 n23 = pkfma(splat2(v2), x3, splat2(v3) * x2);
  f32x2 num = pkfma(n01, p23, n23 * p01);
  f32x2 den = p01 * p23;
  f32x2 r;
  r.x = frcp(den.x);
  r.y = frcp(den.y);
  s = pkfma(num, r, s);
}

// ---------------------------------------------------------------------------
// k_pre: fused projections + value transpose (r12, unchanged).
// ---------------------------------------------------------------------------
__global__ __launch_bounds__(256) void k_pre(
    const float* __restrict__ query, const float* __restrict__ key,
    const float* __restrict__ w1, const float* __restrict__ w2,
    const float* __restrict__ value,
    float* __restrict__ Aout, unsigned short* __restrict__ BoutT,
    unsigned short* __restrict__ valT) {
  __shared__ __align__(16) char Abuf[16 * 128];   // [m][k] bf16, swizzled
  __shared__ __align__(16) char Bbuf[128 * 128];  // [n][k] bf16, swizzled
  __shared__ unsigned short ts[64][66];           // valT transpose buffer

  const int t = threadIdx.x;

  if (blockIdx.y == 0) {  // ---- projections ----
    const int px = blockIdx.x;
    const bool isB = px >= 256;
    const float* in = isB ? key : query;
    const float* wm = isB ? w2 : w1;
    const int m0g = (px & 255) * 16;
    const int w = t >> 6, l = t & 63;

    f32x4v acc[2];
    acc[0] = 0;
    acc[1] = 0;

    float4 aS;
    float4 wS[4][2];

#define P_LOAD(k0_)                                                        \
  {                                                                        \
    aS = *(const float4*)&in[(m0g + (t >> 4)) * 512 + (k0_) + (t & 15) * 4]; \
    _Pragma("unroll") for (int i = 0; i < 4; ++i) {                        \
      int tt = t + i * 256;                                                \
      int row = tt >> 3, g = tt & 7;                                       \
      const float* src = &wm[row * 512 + (k0_) + g * 8];                   \
      wS[i][0] = *(const float4*)src;                                      \
      wS[i][1] = *(const float4*)(src + 4);                                \
    }                                                                      \
  }
#define P_WRITE()                                                          \
  {                                                                        \
    int arow = t >> 4, q4 = t & 15;                                        \
    *(uint2*)(Abuf + arow * 128 + (((q4 >> 1) ^ (arow & 7)) << 4) +        \
              ((q4 & 1) << 3)) =                                           \
        make_uint2(pack2bf(aS.x, aS.y), pack2bf(aS.z, aS.w));              \
    _Pragma("unroll") for (int i = 0; i < 4; ++i) {                        \
      int tt = t + i * 256;                                                \
      int row = tt >> 3, g = tt & 7;                                       \
      uint4 p = make_uint4(                                                \
          pack2bf(wS[i][0].x, wS[i][0].y), pack2bf(wS[i][0].z, wS[i][0].w),\
          pack2bf(wS[i][1].x, wS[i][1].y), pack2bf(wS[i][1].z, wS[i][1].w));\
      *(uint4*)(Bbuf + row * 128 + ((g ^ (row & 7)) << 4)) = p;            \
    }                                                                      \
  }

    P_LOAD(0);
#pragma unroll
    for (int ks8 = 0; ks8 < 8; ++ks8) {
      if (ks8) __syncthreads();
      P_WRITE();
      if (ks8 < 7) P_LOAD(ks8 * 64 + 64);
      __syncthreads();
#pragma unroll
      for (int ks = 0; ks < 2; ++ks) {
        const int gb = ks * 4 + (l >> 4);
        const int ra = l & 15;
        short8 af = *(const short8*)(Abuf + ra * 128 + ((gb ^ (ra & 7)) << 4));
#pragma unroll
        for (int ni = 0; ni < 2; ++ni) {
          const int rb = w * 32 + ni * 16 + (l & 15);
          short8 bf_ = *(const short8*)(Bbuf + rb * 128 + ((gb ^ (rb & 7)) << 4));
          if (isB)
            acc[ni] = __builtin_amdgcn_mfma_f32_16x16x32_bf16(bf_, af, acc[ni], 0, 0, 0);
          else
            acc[ni] = __builtin_amdgcn_mfma_f32_16x16x32_bf16(af, bf_, acc[ni], 0, 0, 0);
        }
      }
    }
#undef P_LOAD
#undef P_WRITE
    if (!isB) {
#pragma unroll
      for (int ni = 0; ni < 2; ++ni) {
        int col = w * 32 + ni * 16 + (l & 15);  // h
#pragma unroll
        for (int j = 0; j < 4; ++j) {
          int row = m0g + (l >> 4) * 4 + j;  // m
          Aout[row * 128 + col] = fexp2(acc[ni][j] * TWO_LOG2E);
        }
      }
    } else {
      int m = m0g + (l & 15);  // contiguous across lanes
#pragma unroll
      for (int ni = 0; ni < 2; ++ni)
#pragma unroll
        for (int j = 0; j < 4; ++j) {
          int h = w * 32 + ni * 16 + (l >> 4) * 4 + j;
          BoutT[h * 4096 + m] = f2bf(fexp2(acc[ni][j] * TWO_LOG2E));
        }
    }
  } else {  // ---- valT ----
    const int x = blockIdx.x;
    const int b = x >> 6, k0 = ((x >> 3) & 7) * 64, n0 = (x & 7) * 64;
    {
      int kr = t >> 4, n4 = (t & 15) * 4;
#pragma unroll
      for (int i = 0; i < 4; ++i) {
        float4 f =
            *(const float4*)&value[((b * 512) + k0 + kr + 16 * i) * 512 + n0 + n4];
        *(ushort4*)&ts[kr + 16 * i][n4] =
            make_ushort4(f2bf(f.x), f2bf(f.y), f2bf(f.z), f2bf(f.w));
      }
    }
    __syncthreads();
    {
      int nw = t >> 4, k4 = (t & 15) * 4;
#pragma unroll
      for (int i = 0; i < 4; ++i) {
        int n = nw + 16 * i;
        ushort4 o = make_ushort4(ts[k4 + 0][n], ts[k4 + 1][n], ts[k4 + 2][n],
                                 ts[k4 + 3][n]);
        *(ushort4*)&valT[((b * 512) + n0 + n) * 512 + k0 + k4] = o;
      }
    }
  }
}

// ---------------------------------------------------------------------------
// K2 (r12 structure, verified 61.6 µs): 4 q-rows/block, in-loop coalesced B
// dword loads from BexpT[h][k], A/v SGPR-broadcast via 5x s_load_dwordx8 per
// 8-h chunk. Packed-f32 math over k-parity. Softmax WITHOUT min-pass
// (|S| <= sum|v| ~ 9 -> exp(-2S) <= e^22, shift-invariant; verified r13).
// grid (128,8) = 4 blocks/CU, block 256 (waves = k-quarters).
// ---------------------------------------------------------------------------
__global__ __launch_bounds__(256, 4) void k_score_softmax(
    const float* __restrict__ Aexp, const unsigned short* __restrict__ BexpT,
    const float* __restrict__ vw, float* __restrict__ attn) {
  __shared__ float red[4][4];

  const int tid = threadIdx.x;
  const int b = blockIdx.y;
  const int qbase = blockIdx.x * 4;
  const int wav = tid >> 6;   // k-quarter
  const int lane = tid & 63;

  const unsigned* const bbase32 = (const unsigned*)(BexpT + b * 512);
  const int kidx = wav * 64 + lane;  // dword index within a k-row

  const float* const pa0 =
      Aexp + __builtin_amdgcn_readfirstlane((b * 512 + qbase) * 128);
  const float* const pa1 = pa0 + 128;
  const float* const pa2 = pa0 + 256;
  const float* const pa3 = pa0 + 384;
  const float* const pv = vw;

  f32x2 acc0 = {0.f, 0.f}, acc1 = {0.f, 0.f};
  f32x2 acc2 = {0.f, 0.f}, acc3 = {0.f, 0.f};

#pragma unroll
  for (int ch = 0; ch < 16; ++ch) {  // 8 h per chunk
    f32x8s sa0, sa1, sa2, sa3, sv;
    unsigned soff = (unsigned)(ch * 32);
    asm volatile(
        "s_load_dwordx8 %0, %5, %10\n\t"
        "s_load_dwordx8 %1, %6, %10\n\t"
        "s_load_dwordx8 %2, %7, %10\n\t"
        "s_load_dwordx8 %3, %8, %10\n\t"
        "s_load_dwordx8 %4, %9, %10"
        : "=&s"(sa0), "=&s"(sa1), "=&s"(sa2), "=&s"(sa3), "=&s"(sv)
        : "s"(pa0), "s"(pa1), "s"(pa2), "s"(pa3), "s"(pv), "s"(soff));

    unsigned u[8];
#pragma unroll
    for (int j = 0; j < 8; ++j)
      u[j] = bbase32[ch * 16384 + j * 2048 + kidx];

    asm volatile("s_waitcnt lgkmcnt(0)"
                 : "+s"(sa0), "+s"(sa1), "+s"(sa2), "+s"(sa3), "+s"(sv));

#pragma unroll
    for (int g = 0; g < 2; ++g) {
      f32x2 b0 = unpack_bf2(u[g * 4 + 0]);
      f32x2 b1 = unpack_bf2(u[g * 4 + 1]);
      f32x2 b2 = unpack_bf2(u[g * 4 + 2]);
      f32x2 b3 = unpack_bf2(u[g * 4 + 3]);
      const int h = g * 4;
      cell4k(sa0[h], sa0[h + 1], sa0[h + 2], sa0[h + 3], b0, b1, b2, b3,
             sv[h], sv[h + 1], sv[h + 2], sv[h + 3], acc0);
      cell4k(sa1[h], sa1[h + 1], sa1[h + 2], sa1[h + 3], b0, b1, b2, b3,
             sv[h], sv[h + 1], sv[h + 2], sv[h + 3], acc1);
      cell4k(sa2[h], sa2[h + 1], sa2[h + 2], sa2[h + 3], b0, b1, b2, b3,
             sv[h], sv[h + 1], sv[h + 2], sv[h + 3], acc2);
      cell4k(sa3[h], sa3[h + 1], sa3[h + 2], sa3[h + 3], b0, b1, b2, b3,
             sv[h], sv[h + 1], sv[h + 2], sv[h + 3], acc3);
    }
  }

  // attn = exp(-2S)/sum (no max-subtraction: |S|<=sum|v|~9, e^22 safe).
  float P0e = fexp2(acc0.x * -TWO_LOG2E);
  float P0o = fexp2(acc0.y * -TWO_LOG2E);
  float P1e = fexp2(acc1.x * -TWO_LOG2E);
  float P1o = fexp2(acc1.y * -TWO_LOG2E);
  float P2e = fexp2(acc2.x * -TWO_LOG2E);
  float P2o = fexp2(acc2.y * -TWO_LOG2E);
  float P3e = fexp2(acc3.x * -TWO_LOG2E);
  float P3o = fexp2(acc3.y * -TWO_LOG2E);
  float s0 = P0e + P0o, s1 = P1e + P1o, s2 = P2e + P2o, s3 = P3e + P3o;
#pragma unroll
  for (int off = 32; off > 0; off >>= 1) {
    s0 += __shfl_xor(s0, off);
    s1 += __shfl_xor(s1, off);
    s2 += __shfl_xor(s2, off);
    s3 += __shfl_xor(s3, off);
  }
  if (lane == 0) {
    red[wav][0] = s0; red[wav][1] = s1; red[wav][2] = s2; red[wav][3] = s3;
  }
  __syncthreads();
  float r0 = frcp(red[0][0] + red[1][0] + red[2][0] + red[3][0]);
  float r1 = frcp(red[0][1] + red[1][1] + red[2][1] + red[3][1]);
  float r2 = frcp(red[0][2] + red[1][2] + red[2][2] + red[3][2]);
  float r3 = frcp(red[0][3] + red[1][3] + red[2][3] + red[3][3]);

  const int row0 = (b * 512 + qbase) * 512;
  const int k0 = kidx * 2;
  *(float2*)&attn[row0 + k0] = make_float2(P0e * r0, P0o * r0);
  *(float2*)&attn[row0 + 512 + k0] = make_float2(P1e * r1, P1o * r1);
  *(float2*)&attn[row0 + 1024 + k0] = make_float2(P2e * r2, P2o * r2);
  *(float2*)&attn[row0 + 1536 + k0] = make_float2(P3e * r3, P3o * r3);
}

// ---------------------------------------------------------------------------
// K3: context[b] = attn[b] @ value[b] via bf16 MFMA 16x16x32 (unchanged).
// ---------------------------------------------------------------------------
__global__ __launch_bounds__(256) void k_context_mfma(
    const float* __restrict__ attn, const unsigned short* __restrict__ valT,
    float* __restrict__ ctx) {
  __shared__ __align__(16) char At[64 * 128];
  __shared__ __align__(16) char Bt[64 * 128];

  const int t = threadIdx.x;
  const int b = blockIdx.z;
  const int m0 = blockIdx.y * 64, n0 = blockIdx.x * 64;
  const int w = t >> 6, l = t & 63;
  const int wr = w >> 1, wc = w & 1;

  f32x4v acc[2][2];
  acc[0][0] = 0; acc[0][1] = 0; acc[1][0] = 0; acc[1][1] = 0;

  const int sr = t >> 2;
  const int sg = (t & 3);
  const int sswz = sr & 7;

  for (int k0 = 0; k0 < 512; k0 += 64) {
    if (k0) __syncthreads();
    {
      const float* src = &attn[(b * 512 + m0 + sr) * 512 + k0 + sg * 16];
      char* dst = At + sr * 128;
#pragma unroll
      for (int h = 0; h < 2; ++h) {
        float4 f0 = *(const float4*)(src + h * 8);
        float4 f1 = *(const float4*)(src + h * 8 + 4);
        uint4 p = make_uint4(pack2bf(f0.x, f0.y), pack2bf(f0.z, f0.w),
                             pack2bf(f1.x, f1.y), pack2bf(f1.z, f1.w));
        int g = sg * 2 + h;
        *(uint4*)(dst + ((g ^ sswz) << 4)) = p;
      }
      const unsigned short* srcb = &valT[(b * 512 + n0 + sr) * 512 + k0];
      char* dstb = Bt + sr * 128;
#pragma unroll
      for (int h = 0; h < 2; ++h) {
        int g = sg + h * 4;
        uint4 vb = *(const uint4*)(srcb + g * 8);
        *(uint4*)(dstb + ((g ^ sswz) << 4)) = vb;
      }
    }
    __syncthreads();
#pragma unroll
    for (int ks = 0; ks < 2; ++ks) {
      const int gb = ks * 4 + (l >> 4);
      short8 af[2], bf_[2];
#pragma unroll
      for (int mi = 0; mi < 2; ++mi) {
        int ra = wr * 32 + mi * 16 + (l & 15);
        af[mi] = *(const short8*)(At + ra * 128 + ((gb ^ (ra & 7)) << 4));
      }
#pragma unroll
      for (int ni = 0; ni < 2; ++ni) {
        int rb = wc * 32 + ni * 16 + (l & 15);
        bf_[ni] = *(const short8*)(Bt + rb * 128 + ((gb ^ (rb & 7)) << 4));
      }
#pragma unroll
      for (int mi = 0; mi < 2; ++mi)
#pragma unroll
        for (int ni = 0; ni < 2; ++ni)
          acc[mi][ni] = __builtin_amdgcn_mfma_f32_16x16x32_bf16(
              af[mi], bf_[ni], acc[mi][ni], 0, 0, 0);
    }
  }
  __syncthreads();
#pragma unroll
  for (int mi = 0; mi < 2; ++mi)
#pragma unroll
    for (int ni = 0; ni < 2; ++ni) {
      int col = n0 + wc * 32 + ni * 16 + (l & 15);
#pragma unroll
      for (int j = 0; j < 4; ++j) {
        int row = m0 + wr * 32 + mi * 16 + (l >> 4) * 4 + j;
        ctx[(b * 512 + row) * 512 + col] = acc[mi][ni][j];
      }
    }
}

extern "C" void kernel_launch(void* const* d_in, const int* in_sizes, int n_in,
                              void* d_out, int out_size, void* d_ws, size_t ws_size,
                              hipStream_t stream) {
  const float* query = (const float*)d_in[0];
  const float* key   = (const float*)d_in[1];
  const float* value = (const float*)d_in[2];
  const float* w1    = (const float*)d_in[3];
  const float* w2    = (const float*)d_in[4];
  const float* v     = (const float*)d_in[5];

  float* attn = (float*)d_out;
  float* ctx  = attn + 8 * 512 * 512;

  float* Aexp = (float*)d_ws;                                    // 4096*128 f32
  unsigned short* BexpT = (unsigned short*)(Aexp + 4096 * 128);  // 128*4096 bf16
  unsigned short* valT = BexpT + 128 * 4096;                     // 8*512*512 bf16

  k_pre<<<dim3(512, 2), 256, 0, stream>>>(query, key, w1, w2, value,
                                          Aexp, BexpT, valT);
  k_score_softmax<<<dim3(128, 8), 256, 0, stream>>>(Aexp, BexpT, v, attn);
  k_context_mfma<<<dim3(8, 8, 8), 256, 0, stream>>>(attn, valT, ctx);
}

// Round 17
// 60.107 us; speedup vs baseline: 1.0420x; 1.0040x over previous
//
#include <hip/hip_runtime.h>

#define TWO_LOG2E 2.8853900817779268f

__device__ __forceinline__ float frcp(float x) {
#if __has_builtin(__builtin_amdgcn_rcpf)
  return __builtin_amdgcn_rcpf(x);
#else
  return 1.0f / x;
#endif
}
__device__ __forceinline__ float fexp2(float x) {
#if __has_builtin(__builtin_amdgcn_exp2f)
  return __builtin_amdgcn_exp2f(x);
#else
  return exp2f(x);
#endif
}
__device__ __forceinline__ unsigned short f2bf(float f) {  // RNE f32->bf16
  unsigned int u = __float_as_uint(f);
  u += 0x7fffu + ((u >> 16) & 1u);
  return (unsigned short)(u >> 16);
}
__device__ __forceinline__ unsigned int pack2bf(float lo, float hi) {
  return (unsigned int)f2bf(lo) | ((unsigned int)f2bf(hi) << 16);
}

using short8 = __attribute__((ext_vector_type(8))) short;
using f32x4v = __attribute__((ext_vector_type(4))) float;
using f32x8s = __attribute__((ext_vector_type(8))) float;
using f32x2 = __attribute__((ext_vector_type(2))) float;

__device__ __forceinline__ f32x2 pkfma(f32x2 a, f32x2 b, f32x2 c) {
  return __builtin_elementwise_fma(a, b, c);
}
__device__ __forceinline__ f32x2 splat2(float x) {
  f32x2 r;
  r.x = x;
  r.y = x;
  return r;
}
__device__ __forceinline__ f32x2 unpack_bf2(unsigned u) {  // (k-even, k-odd)
  f32x2 r;
  r.x = __uint_as_float(u << 16);
  r.y = __uint_as_float(u & 0xffff0000u);
  return r;
}
// s += sum_{i=0..3} v_i/(a_i*b_i+1) for BOTH k-parities, ONE rcp per parity.
__device__ __forceinline__ void cell4k(float a0, float a1, float a2, float a3,
                                       f32x2 b0, f32x2 b1, f32x2 b2, f32x2 b3,
                                       float v0, float v1, float v2, float v3,
                                       f32x2& s) {
  const f32x2 one = {1.f, 1.f};
  f32x2 x0 = pkfma(splat2(a0), b0, one);
  f32x2 x1 = pkfma(splat2(a1), b1, one);
  f32x2 x2 = pkfma(splat2(a2), b2, one);
  f32x2 x3 = pkfma(splat2(a3), b3, one);
  f32x2 p01 = x0 * x1, p23 = x2 * x3;
  f32x2 n01 = pkfma(splat2(v0), x1, splat2(v1) * x0);
  f32x2 n23 = pkfma(splat2(v2), x3, splat2(v3) * x2);
  f32x2 num = pkfma(n01, p23, n23 * p01);
  f32x2 den = p01 * p23;
  f32x2 r;
  r.x = frcp(den.x);
  r.y = frcp(den.y);
  s = pkfma(num, r, s);
}

// ---------------------------------------------------------------------------
// k_pre: fused projections + value transpose (r12, unchanged).
// ---------------------------------------------------------------------------
__global__ __launch_bounds__(256) void k_pre(
    const float* __restrict__ query, const float* __restrict__ key,
    const float* __restrict__ w1, const float* __restrict__ w2,
    const float* __restrict__ value,
    float* __restrict__ Aout, unsigned short* __restrict__ BoutT,
    unsigned short* __restrict__ valT) {
  __shared__ __align__(16) char Abuf[16 * 128];   // [m][k] bf16, swizzled
  __shared__ __align__(16) char Bbuf[128 * 128];  // [n][k] bf16, swizzled
  __shared__ unsigned short ts[64][66];           // valT transpose buffer

  const int t = threadIdx.x;

  if (blockIdx.y == 0) {  // ---- projections ----
    const int px = blockIdx.x;
    const bool isB = px >= 256;
    const float* in = isB ? key : query;
    const float* wm = isB ? w2 : w1;
    const int m0g = (px & 255) * 16;
    const int w = t >> 6, l = t & 63;

    f32x4v acc[2];
    acc[0] = 0;
    acc[1] = 0;

    float4 aS;
    float4 wS[4][2];

#define P_LOAD(k0_)                                                        \
  {                                                                        \
    aS = *(const float4*)&in[(m0g + (t >> 4)) * 512 + (k0_) + (t & 15) * 4]; \
    _Pragma("unroll") for (int i = 0; i < 4; ++i) {                        \
      int tt = t + i * 256;                                                \
      int row = tt >> 3, g = tt & 7;                                       \
      const float* src = &wm[row * 512 + (k0_) + g * 8];                   \
      wS[i][0] = *(const float4*)src;                                      \
      wS[i][1] = *(const float4*)(src + 4);                                \
    }                                                                      \
  }
#define P_WRITE()                                                          \
  {                                                                        \
    int arow = t >> 4, q4 = t & 15;                                        \
    *(uint2*)(Abuf + arow * 128 + (((q4 >> 1) ^ (arow & 7)) << 4) +        \
              ((q4 & 1) << 3)) =                                           \
        make_uint2(pack2bf(aS.x, aS.y), pack2bf(aS.z, aS.w));              \
    _Pragma("unroll") for (int i = 0; i < 4; ++i) {                        \
      int tt = t + i * 256;                                                \
      int row = tt >> 3, g = tt & 7;                                       \
      uint4 p = make_uint4(                                                \
          pack2bf(wS[i][0].x, wS[i][0].y), pack2bf(wS[i][0].z, wS[i][0].w),\
          pack2bf(wS[i][1].x, wS[i][1].y), pack2bf(wS[i][1].z, wS[i][1].w));\
      *(uint4*)(Bbuf + row * 128 + ((g ^ (row & 7)) << 4)) = p;            \
    }                                                                      \
  }

    P_LOAD(0);
#pragma unroll
    for (int ks8 = 0; ks8 < 8; ++ks8) {
      if (ks8) __syncthreads();
      P_WRITE();
      if (ks8 < 7) P_LOAD(ks8 * 64 + 64);
      __syncthreads();
#pragma unroll
      for (int ks = 0; ks < 2; ++ks) {
        const int gb = ks * 4 + (l >> 4);
        const int ra = l & 15;
        short8 af = *(const short8*)(Abuf + ra * 128 + ((gb ^ (ra & 7)) << 4));
#pragma unroll
        for (int ni = 0; ni < 2; ++ni) {
          const int rb = w * 32 + ni * 16 + (l & 15);
          short8 bf_ = *(const short8*)(Bbuf + rb * 128 + ((gb ^ (rb & 7)) << 4));
          if (isB)
            acc[ni] = __builtin_amdgcn_mfma_f32_16x16x32_bf16(bf_, af, acc[ni], 0, 0, 0);
          else
            acc[ni] = __builtin_amdgcn_mfma_f32_16x16x32_bf16(af, bf_, acc[ni], 0, 0, 0);
        }
      }
    }
#undef P_LOAD
#undef P_WRITE
    if (!isB) {
#pragma unroll
      for (int ni = 0; ni < 2; ++ni) {
        int col = w * 32 + ni * 16 + (l & 15);  // h
#pragma unroll
        for (int j = 0; j < 4; ++j) {
          int row = m0g + (l >> 4) * 4 + j;  // m
          Aout[row * 128 + col] = fexp2(acc[ni][j] * TWO_LOG2E);
        }
      }
    } else {
      int m = m0g + (l & 15);  // contiguous across lanes
#pragma unroll
      for (int ni = 0; ni < 2; ++ni)
#pragma unroll
        for (int j = 0; j < 4; ++j) {
          int h = w * 32 + ni * 16 + (l >> 4) * 4 + j;
          BoutT[h * 4096 + m] = f2bf(fexp2(acc[ni][j] * TWO_LOG2E));
        }
    }
  } else {  // ---- valT ----
    const int x = blockIdx.x;
    const int b = x >> 6, k0 = ((x >> 3) & 7) * 64, n0 = (x & 7) * 64;
    {
      int kr = t >> 4, n4 = (t & 15) * 4;
#pragma unroll
      for (int i = 0; i < 4; ++i) {
        float4 f =
            *(const float4*)&value[((b * 512) + k0 + kr + 16 * i) * 512 + n0 + n4];
        *(ushort4*)&ts[kr + 16 * i][n4] =
            make_ushort4(f2bf(f.x), f2bf(f.y), f2bf(f.z), f2bf(f.w));
      }
    }
    __syncthreads();
    {
      int nw = t >> 4, k4 = (t & 15) * 4;
#pragma unroll
      for (int i = 0; i < 4; ++i) {
        int n = nw + 16 * i;
        ushort4 o = make_ushort4(ts[k4 + 0][n], ts[k4 + 1][n], ts[k4 + 2][n],
                                 ts[k4 + 3][n]);
        *(ushort4*)&valT[((b * 512) + n0 + n) * 512 + k0 + k4] = o;
      }
    }
  }
}

// ---------------------------------------------------------------------------
// K2: S[q,k] = sum_h v[h]/(A[q,h]*B[k,h]+1);  attn = softmax_k(-2S).
// 4 q-rows/block, 512 threads = 8 waves: waves 0-3 compute h in [0,64),
// waves 4-7 h in [64,128). Partials combined via one 16KB LDS exchange
// (tid^256 partner). A/v SGPR-broadcast (s_load_dwordx8; h-half offset forced
// scalar via readfirstlane -- r16's compile fail was a VGPR in an "s"
// constraint). B in-loop coalesced dwords, packed-f32 over k-parity.
// No min-pass (|S| <= sum|v| ~ 9). grid (128,8), block 512 -> 8 waves/SIMD.
// ---------------------------------------------------------------------------
__global__ __launch_bounds__(512, 8) void k_score_softmax(
    const float* __restrict__ Aexp, const unsigned short* __restrict__ BexpT,
    const float* __restrict__ vw, float* __restrict__ attn) {
  __shared__ __align__(16) f32x2 part[512][4];  // 16KB partial-S exchange
  __shared__ float red[8][4];

  const int tid = threadIdx.x;
  const int b = blockIdx.y;
  const int qbase = blockIdx.x * 4;
  const int wav = tid >> 6;
  const int hgrp = wav >> 2;  // h-half 0/1
  const int kq = wav & 3;     // k-quarter
  const int lane = tid & 63;

  const unsigned* const bbase32 = (const unsigned*)(BexpT + b * 512);
  const int kidx = kq * 64 + lane;  // dword index within a k-row

  const float* const pa0 =
      Aexp + __builtin_amdgcn_readfirstlane((b * 512 + qbase) * 128);
  const float* const pa1 = pa0 + 128;
  const float* const pa2 = pa0 + 256;
  const float* const pa3 = pa0 + 384;
  const float* const pv = vw;
  // wave-uniform h-half byte offset, forced into an SGPR
  const unsigned hoff = (unsigned)__builtin_amdgcn_readfirstlane(hgrp * 256);

  f32x2 acc0 = {0.f, 0.f}, acc1 = {0.f, 0.f};
  f32x2 acc2 = {0.f, 0.f}, acc3 = {0.f, 0.f};

#pragma unroll
  for (int ch = 0; ch < 8; ++ch) {  // 8 chunks x 8 h (this h-half)
    f32x8s sa0, sa1, sa2, sa3, sv;
    unsigned soff = hoff + (unsigned)(ch * 32);
    asm volatile(
        "s_load_dwordx8 %0, %5, %10\n\t"
        "s_load_dwordx8 %1, %6, %10\n\t"
        "s_load_dwordx8 %2, %7, %10\n\t"
        "s_load_dwordx8 %3, %8, %10\n\t"
        "s_load_dwordx8 %4, %9, %10"
        : "=&s"(sa0), "=&s"(sa1), "=&s"(sa2), "=&s"(sa3), "=&s"(sv)
        : "s"(pa0), "s"(pa1), "s"(pa2), "s"(pa3), "s"(pv), "s"(soff));

    unsigned u[8];
#pragma unroll
    for (int j = 0; j < 8; ++j)
      u[j] = bbase32[hgrp * 131072 + ch * 16384 + j * 2048 + kidx];

    asm volatile("s_waitcnt lgkmcnt(0)"
                 : "+s"(sa0), "+s"(sa1), "+s"(sa2), "+s"(sa3), "+s"(sv));

#pragma unroll
    for (int g = 0; g < 2; ++g) {
      f32x2 b0 = unpack_bf2(u[g * 4 + 0]);
      f32x2 b1 = unpack_bf2(u[g * 4 + 1]);
      f32x2 b2 = unpack_bf2(u[g * 4 + 2]);
      f32x2 b3 = unpack_bf2(u[g * 4 + 3]);
      const int h = g * 4;
      cell4k(sa0[h], sa0[h + 1], sa0[h + 2], sa0[h + 3], b0, b1, b2, b3,
             sv[h], sv[h + 1], sv[h + 2], sv[h + 3], acc0);
      cell4k(sa1[h], sa1[h + 1], sa1[h + 2], sa1[h + 3], b0, b1, b2, b3,
             sv[h], sv[h + 1], sv[h + 2], sv[h + 3], acc1);
      cell4k(sa2[h], sa2[h + 1], sa2[h + 2], sa2[h + 3], b0, b1, b2, b3,
             sv[h], sv[h + 1], sv[h + 2], sv[h + 3], acc2);
      cell4k(sa3[h], sa3[h + 1], sa3[h + 2], sa3[h + 3], b0, b1, b2, b3,
             sv[h], sv[h + 1], sv[h + 2], sv[h + 3], acc3);
    }
  }

  // combine h-halves: partner thread = tid ^ 256 (same q,k; other h-half)
  part[tid][0] = acc0;
  part[tid][1] = acc1;
  part[tid][2] = acc2;
  part[tid][3] = acc3;
  __syncthreads();
  {
    const f32x2* pp = part[tid ^ 256];
    acc0 += pp[0];
    acc1 += pp[1];
    acc2 += pp[2];
    acc3 += pp[3];
  }

  // attn = exp(-2S)/sum (no max-subtraction: |S|<=sum|v|~9, e^22 safe).
  float P0e = fexp2(acc0.x * -TWO_LOG2E);
  float P0o = fexp2(acc0.y * -TWO_LOG2E);
  float P1e = fexp2(acc1.x * -TWO_LOG2E);
  float P1o = fexp2(acc1.y * -TWO_LOG2E);
  float P2e = fexp2(acc2.x * -TWO_LOG2E);
  float P2o = fexp2(acc2.y * -TWO_LOG2E);
  float P3e = fexp2(acc3.x * -TWO_LOG2E);
  float P3o = fexp2(acc3.y * -TWO_LOG2E);
  float s0 = P0e + P0o, s1 = P1e + P1o, s2 = P2e + P2o, s3 = P3e + P3o;
#pragma unroll
  for (int off = 32; off > 0; off >>= 1) {
    s0 += __shfl_xor(s0, off);
    s1 += __shfl_xor(s1, off);
    s2 += __shfl_xor(s2, off);
    s3 += __shfl_xor(s3, off);
  }
  if (lane == 0) {
    red[wav][0] = s0; red[wav][1] = s1; red[wav][2] = s2; red[wav][3] = s3;
  }
  __syncthreads();
  const int rb = hgrp * 4;  // sum this h-group's four k-quarter waves
  float r0 = frcp(red[rb][0] + red[rb + 1][0] + red[rb + 2][0] + red[rb + 3][0]);
  float r1 = frcp(red[rb][1] + red[rb + 1][1] + red[rb + 2][1] + red[rb + 3][1]);
  float r2 = frcp(red[rb][2] + red[rb + 1][2] + red[rb + 2][2] + red[rb + 3][2]);
  float r3 = frcp(red[rb][3] + red[rb + 1][3] + red[rb + 2][3] + red[rb + 3][3]);

  // each h-group stores 2 of the 4 q-rows (data identical post-combine)
  const int row0 = (b * 512 + qbase) * 512;
  const int k0 = kidx * 2;
  if (hgrp == 0) {
    *(float2*)&attn[row0 + k0] = make_float2(P0e * r0, P0o * r0);
    *(float2*)&attn[row0 + 512 + k0] = make_float2(P1e * r1, P1o * r1);
  } else {
    *(float2*)&attn[row0 + 1024 + k0] = make_float2(P2e * r2, P2o * r2);
    *(float2*)&attn[row0 + 1536 + k0] = make_float2(P3e * r3, P3o * r3);
  }
}

// ---------------------------------------------------------------------------
// K3: context[b] = attn[b] @ value[b] via bf16 MFMA 16x16x32 (unchanged).
// ---------------------------------------------------------------------------
__global__ __launch_bounds__(256) void k_context_mfma(
    const float* __restrict__ attn, const unsigned short* __restrict__ valT,
    float* __restrict__ ctx) {
  __shared__ __align__(16) char At[64 * 128];
  __shared__ __align__(16) char Bt[64 * 128];

  const int t = threadIdx.x;
  const int b = blockIdx.z;
  const int m0 = blockIdx.y * 64, n0 = blockIdx.x * 64;
  const int w = t >> 6, l = t & 63;
  const int wr = w >> 1, wc = w & 1;

  f32x4v acc[2][2];
  acc[0][0] = 0; acc[0][1] = 0; acc[1][0] = 0; acc[1][1] = 0;

  const int sr = t >> 2;
  const int sg = (t & 3);
  const int sswz = sr & 7;

  for (int k0 = 0; k0 < 512; k0 += 64) {
    if (k0) __syncthreads();
    {
      const float* src = &attn[(b * 512 + m0 + sr) * 512 + k0 + sg * 16];
      char* dst = At + sr * 128;
#pragma unroll
      for (int h = 0; h < 2; ++h) {
        float4 f0 = *(const float4*)(src + h * 8);
        float4 f1 = *(const float4*)(src + h * 8 + 4);
        uint4 p = make_uint4(pack2bf(f0.x, f0.y), pack2bf(f0.z, f0.w),
                             pack2bf(f1.x, f1.y), pack2bf(f1.z, f1.w));
        int g = sg * 2 + h;
        *(uint4*)(dst + ((g ^ sswz) << 4)) = p;
      }
      const unsigned short* srcb = &valT[(b * 512 + n0 + sr) * 512 + k0];
      char* dstb = Bt + sr * 128;
#pragma unroll
      for (int h = 0; h < 2; ++h) {
        int g = sg + h * 4;
        uint4 vb = *(const uint4*)(srcb + g * 8);
        *(uint4*)(dstb + ((g ^ sswz) << 4)) = vb;
      }
    }
    __syncthreads();
#pragma unroll
    for (int ks = 0; ks < 2; ++ks) {
      const int gb = ks * 4 + (l >> 4);
      short8 af[2], bf_[2];
#pragma unroll
      for (int mi = 0; mi < 2; ++mi) {
        int ra = wr * 32 + mi * 16 + (l & 15);
        af[mi] = *(const short8*)(At + ra * 128 + ((gb ^ (ra & 7)) << 4));
      }
#pragma unroll
      for (int ni = 0; ni < 2; ++ni) {
        int rb = wc * 32 + ni * 16 + (l & 15);
        bf_[ni] = *(const short8*)(Bt + rb * 128 + ((gb ^ (rb & 7)) << 4));
      }
#pragma unroll
      for (int mi = 0; mi < 2; ++mi)
#pragma unroll
        for (int ni = 0; ni < 2; ++ni)
          acc[mi][ni] = __builtin_amdgcn_mfma_f32_16x16x32_bf16(
              af[mi], bf_[ni], acc[mi][ni], 0, 0, 0);
    }
  }
  __syncthreads();
#pragma unroll
  for (int mi = 0; mi < 2; ++mi)
#pragma unroll
    for (int ni = 0; ni < 2; ++ni) {
      int col = n0 + wc * 32 + ni * 16 + (l & 15);
#pragma unroll
      for (int j = 0; j < 4; ++j) {
        int row = m0 + wr * 32 + mi * 16 + (l >> 4) * 4 + j;
        ctx[(b * 512 + row) * 512 + col] = acc[mi][ni][j];
      }
    }
}

extern "C" void kernel_launch(void* const* d_in, const int* in_sizes, int n_in,
                              void* d_out, int out_size, void* d_ws, size_t ws_size,
                              hipStream_t stream) {
  const float* query = (const float*)d_in[0];
  const float* key   = (const float*)d_in[1];
  const float* value = (const float*)d_in[2];
  const float* w1    = (const float*)d_in[3];
  const float* w2    = (const float*)d_in[4];
  const float* v     = (const float*)d_in[5];

  float* attn = (float*)d_out;
  float* ctx  = attn + 8 * 512 * 512;

  float* Aexp = (float*)d_ws;                                    // 4096*128 f32
  unsigned short* BexpT = (unsigned short*)(Aexp + 4096 * 128);  // 128*4096 bf16
  unsigned short* valT = BexpT + 128 * 4096;                     // 8*512*512 bf16

  k_pre<<<dim3(512, 2), 256, 0, stream>>>(query, key, w1, w2, value,
                                          Aexp, BexpT, valT);
  k_score_softmax<<<dim3(128, 8), 512, 0, stream>>>(Aexp, BexpT, v, attn);
  k_context_mfma<<<dim3(8, 8, 8), 256, 0, stream>>>(attn, valT, ctx);
}

// Round 18
// 58.126 us; speedup vs baseline: 1.0775x; 1.0341x over previous
//
#include <hip/hip_runtime.h>

#define TWO_LOG2E 2.8853900817779268f

__device__ __forceinline__ float frcp(float x) {
#if __has_builtin(__builtin_amdgcn_rcpf)
  return __builtin_amdgcn_rcpf(x);
#else
  return 1.0f / x;
#endif
}
__device__ __forceinline__ float fexp2(float x) {
#if __has_builtin(__builtin_amdgcn_exp2f)
  return __builtin_amdgcn_exp2f(x);
#else
  return exp2f(x);
#endif
}
__device__ __forceinline__ unsigned short f2bf(float f) {  // RNE f32->bf16
  unsigned int u = __float_as_uint(f);
  u += 0x7fffu + ((u >> 16) & 1u);
  return (unsigned short)(u >> 16);
}
__device__ __forceinline__ unsigned int pack2bf(float lo, float hi) {
  return (unsigned int)f2bf(lo) | ((unsigned int)f2bf(hi) << 16);
}

using short8 = __attribute__((ext_vector_type(8))) short;
using f32x4v = __attribute__((ext_vector_type(4))) float;
using f32x8s = __attribute__((ext_vector_type(8))) float;
using f32x2 = __attribute__((ext_vector_type(2))) float;

__device__ __forceinline__ f32x2 pkfma(f32x2 a, f32x2 b, f32x2 c) {
  return __builtin_elementwise_fma(a, b, c);
}
__device__ __forceinline__ f32x2 splat2(float x) {
  f32x2 r;
  r.x = x;
  r.y = x;
  return r;
}
__device__ __forceinline__ f32x2 unpack_bf2(unsigned u) {  // (k-even, k-odd)
  f32x2 r;
  r.x = __uint_as_float(u << 16);
  r.y = __uint_as_float(u & 0xffff0000u);
  return r;
}
// s += sum_{i=0..3} v_i/(a_i*b_i+1) for BOTH k-parities, ONE rcp per parity.
__device__ __forceinline__ void cell4k(float a0, float a1, float a2, float a3,
                                       f32x2 b0, f32x2 b1, f32x2 b2, f32x2 b3,
                                       float v0, float v1, float v2, float v3,
                                       f32x2& s) {
  const f32x2 one = {1.f, 1.f};
  f32x2 x0 = pkfma(splat2(a0), b0, one);
  f32x2 x1 = pkfma(splat2(a1), b1, one);
  f32x2 x2 = pkfma(splat2(a2), b2, one);
  f32x2 x3 = pkfma(splat2(a3), b3, one);
  f32x2 p01 = x0 * x1, p23 = x2 * x3;
  f32x2 n01 = pkfma(splat2(v0), x1, splat2(v1) * x0);
  f32x2 n23 = pkfma(splat2(v2), x3, splat2(v3) * x2);
  f32x2 num = pkfma(n01, p23, n23 * p01);
  f32x2 den = p01 * p23;
  f32x2 r;
  r.x = frcp(den.x);
  r.y = frcp(den.y);
  s = pkfma(num, r, s);
}

// ---------------------------------------------------------------------------
// k_pre: fused projections + value transpose (r12, unchanged).
// ---------------------------------------------------------------------------
__global__ __launch_bounds__(256) void k_pre(
    const float* __restrict__ query, const float* __restrict__ key,
    const float* __restrict__ w1, const float* __restrict__ w2,
    const float* __restrict__ value,
    float* __restrict__ Aout, unsigned short* __restrict__ BoutT,
    unsigned short* __restrict__ valT) {
  __shared__ __align__(16) char Abuf[16 * 128];   // [m][k] bf16, swizzled
  __shared__ __align__(16) char Bbuf[128 * 128];  // [n][k] bf16, swizzled
  __shared__ unsigned short ts[64][66];           // valT transpose buffer

  const int t = threadIdx.x;

  if (blockIdx.y == 0) {  // ---- projections ----
    const int px = blockIdx.x;
    const bool isB = px >= 256;
    const float* in = isB ? key : query;
    const float* wm = isB ? w2 : w1;
    const int m0g = (px & 255) * 16;
    const int w = t >> 6, l = t & 63;

    f32x4v acc[2];
    acc[0] = 0;
    acc[1] = 0;

    float4 aS;
    float4 wS[4][2];

#define P_LOAD(k0_)                                                        \
  {                                                                        \
    aS = *(const float4*)&in[(m0g + (t >> 4)) * 512 + (k0_) + (t & 15) * 4]; \
    _Pragma("unroll") for (int i = 0; i < 4; ++i) {                        \
      int tt = t + i * 256;                                                \
      int row = tt >> 3, g = tt & 7;                                       \
      const float* src = &wm[row * 512 + (k0_) + g * 8];                   \
      wS[i][0] = *(const float4*)src;                                      \
      wS[i][1] = *(const float4*)(src + 4);                                \
    }                                                                      \
  }
#define P_WRITE()                                                          \
  {                                                                        \
    int arow = t >> 4, q4 = t & 15;                                        \
    *(uint2*)(Abuf + arow * 128 + (((q4 >> 1) ^ (arow & 7)) << 4) +        \
              ((q4 & 1) << 3)) =                                           \
        make_uint2(pack2bf(aS.x, aS.y), pack2bf(aS.z, aS.w));              \
    _Pragma("unroll") for (int i = 0; i < 4; ++i) {                        \
      int tt = t + i * 256;                                                \
      int row = tt >> 3, g = tt & 7;                                       \
      uint4 p = make_uint4(                                                \
          pack2bf(wS[i][0].x, wS[i][0].y), pack2bf(wS[i][0].z, wS[i][0].w),\
          pack2bf(wS[i][1].x, wS[i][1].y), pack2bf(wS[i][1].z, wS[i][1].w));\
      *(uint4*)(Bbuf + row * 128 + ((g ^ (row & 7)) << 4)) = p;            \
    }                                                                      \
  }

    P_LOAD(0);
#pragma unroll
    for (int ks8 = 0; ks8 < 8; ++ks8) {
      if (ks8) __syncthreads();
      P_WRITE();
      if (ks8 < 7) P_LOAD(ks8 * 64 + 64);
      __syncthreads();
#pragma unroll
      for (int ks = 0; ks < 2; ++ks) {
        const int gb = ks * 4 + (l >> 4);
        const int ra = l & 15;
        short8 af = *(const short8*)(Abuf + ra * 128 + ((gb ^ (ra & 7)) << 4));
#pragma unroll
        for (int ni = 0; ni < 2; ++ni) {
          const int rb = w * 32 + ni * 16 + (l & 15);
          short8 bf_ = *(const short8*)(Bbuf + rb * 128 + ((gb ^ (rb & 7)) << 4));
          if (isB)
            acc[ni] = __builtin_amdgcn_mfma_f32_16x16x32_bf16(bf_, af, acc[ni], 0, 0, 0);
          else
            acc[ni] = __builtin_amdgcn_mfma_f32_16x16x32_bf16(af, bf_, acc[ni], 0, 0, 0);
        }
      }
    }
#undef P_LOAD
#undef P_WRITE
    if (!isB) {
#pragma unroll
      for (int ni = 0; ni < 2; ++ni) {
        int col = w * 32 + ni * 16 + (l & 15);  // h
#pragma unroll
        for (int j = 0; j < 4; ++j) {
          int row = m0g + (l >> 4) * 4 + j;  // m
          Aout[row * 128 + col] = fexp2(acc[ni][j] * TWO_LOG2E);
        }
      }
    } else {
      int m = m0g + (l & 15);  // contiguous across lanes
#pragma unroll
      for (int ni = 0; ni < 2; ++ni)
#pragma unroll
        for (int j = 0; j < 4; ++j) {
          int h = w * 32 + ni * 16 + (l >> 4) * 4 + j;
          BoutT[h * 4096 + m] = f2bf(fexp2(acc[ni][j] * TWO_LOG2E));
        }
    }
  } else {  // ---- valT ----
    const int x = blockIdx.x;
    const int b = x >> 6, k0 = ((x >> 3) & 7) * 64, n0 = (x & 7) * 64;
    {
      int kr = t >> 4, n4 = (t & 15) * 4;
#pragma unroll
      for (int i = 0; i < 4; ++i) {
        float4 f =
            *(const float4*)&value[((b * 512) + k0 + kr + 16 * i) * 512 + n0 + n4];
        *(ushort4*)&ts[kr + 16 * i][n4] =
            make_ushort4(f2bf(f.x), f2bf(f.y), f2bf(f.z), f2bf(f.w));
      }
    }
    __syncthreads();
    {
      int nw = t >> 4, k4 = (t & 15) * 4;
#pragma unroll
      for (int i = 0; i < 4; ++i) {
        int n = nw + 16 * i;
        ushort4 o = make_ushort4(ts[k4 + 0][n], ts[k4 + 1][n], ts[k4 + 2][n],
                                 ts[k4 + 3][n]);
        *(ushort4*)&valT[((b * 512) + n0 + n) * 512 + k0 + k4] = o;
      }
    }
  }
}

// ---------------------------------------------------------------------------
// K2: (r17, verified 60.1 µs total) — unchanged.
// ---------------------------------------------------------------------------
__global__ __launch_bounds__(512, 8) void k_score_softmax(
    const float* __restrict__ Aexp, const unsigned short* __restrict__ BexpT,
    const float* __restrict__ vw, float* __restrict__ attn) {
  __shared__ __align__(16) f32x2 part[512][4];  // 16KB partial-S exchange
  __shared__ float red[8][4];

  const int tid = threadIdx.x;
  const int b = blockIdx.y;
  const int qbase = blockIdx.x * 4;
  const int wav = tid >> 6;
  const int hgrp = wav >> 2;  // h-half 0/1
  const int kq = wav & 3;     // k-quarter
  const int lane = tid & 63;

  const unsigned* const bbase32 = (const unsigned*)(BexpT + b * 512);
  const int kidx = kq * 64 + lane;  // dword index within a k-row

  const float* const pa0 =
      Aexp + __builtin_amdgcn_readfirstlane((b * 512 + qbase) * 128);
  const float* const pa1 = pa0 + 128;
  const float* const pa2 = pa0 + 256;
  const float* const pa3 = pa0 + 384;
  const float* const pv = vw;
  const unsigned hoff = (unsigned)__builtin_amdgcn_readfirstlane(hgrp * 256);

  f32x2 acc0 = {0.f, 0.f}, acc1 = {0.f, 0.f};
  f32x2 acc2 = {0.f, 0.f}, acc3 = {0.f, 0.f};

#pragma unroll
  for (int ch = 0; ch < 8; ++ch) {  // 8 chunks x 8 h (this h-half)
    f32x8s sa0, sa1, sa2, sa3, sv;
    unsigned soff = hoff + (unsigned)(ch * 32);
    asm volatile(
        "s_load_dwordx8 %0, %5, %10\n\t"
        "s_load_dwordx8 %1, %6, %10\n\t"
        "s_load_dwordx8 %2, %7, %10\n\t"
        "s_load_dwordx8 %3, %8, %10\n\t"
        "s_load_dwordx8 %4, %9, %10"
        : "=&s"(sa0), "=&s"(sa1), "=&s"(sa2), "=&s"(sa3), "=&s"(sv)
        : "s"(pa0), "s"(pa1), "s"(pa2), "s"(pa3), "s"(pv), "s"(soff));

    unsigned u[8];
#pragma unroll
    for (int j = 0; j < 8; ++j)
      u[j] = bbase32[hgrp * 131072 + ch * 16384 + j * 2048 + kidx];

    asm volatile("s_waitcnt lgkmcnt(0)"
                 : "+s"(sa0), "+s"(sa1), "+s"(sa2), "+s"(sa3), "+s"(sv));

#pragma unroll
    for (int g = 0; g < 2; ++g) {
      f32x2 b0 = unpack_bf2(u[g * 4 + 0]);
      f32x2 b1 = unpack_bf2(u[g * 4 + 1]);
      f32x2 b2 = unpack_bf2(u[g * 4 + 2]);
      f32x2 b3 = unpack_bf2(u[g * 4 + 3]);
      const int h = g * 4;
      cell4k(sa0[h], sa0[h + 1], sa0[h + 2], sa0[h + 3], b0, b1, b2, b3,
             sv[h], sv[h + 1], sv[h + 2], sv[h + 3], acc0);
      cell4k(sa1[h], sa1[h + 1], sa1[h + 2], sa1[h + 3], b0, b1, b2, b3,
             sv[h], sv[h + 1], sv[h + 2], sv[h + 3], acc1);
      cell4k(sa2[h], sa2[h + 1], sa2[h + 2], sa2[h + 3], b0, b1, b2, b3,
             sv[h], sv[h + 1], sv[h + 2], sv[h + 3], acc2);
      cell4k(sa3[h], sa3[h + 1], sa3[h + 2], sa3[h + 3], b0, b1, b2, b3,
             sv[h], sv[h + 1], sv[h + 2], sv[h + 3], acc3);
    }
  }

  part[tid][0] = acc0;
  part[tid][1] = acc1;
  part[tid][2] = acc2;
  part[tid][3] = acc3;
  __syncthreads();
  {
    const f32x2* pp = part[tid ^ 256];
    acc0 += pp[0];
    acc1 += pp[1];
    acc2 += pp[2];
    acc3 += pp[3];
  }

  float P0e = fexp2(acc0.x * -TWO_LOG2E);
  float P0o = fexp2(acc0.y * -TWO_LOG2E);
  float P1e = fexp2(acc1.x * -TWO_LOG2E);
  float P1o = fexp2(acc1.y * -TWO_LOG2E);
  float P2e = fexp2(acc2.x * -TWO_LOG2E);
  float P2o = fexp2(acc2.y * -TWO_LOG2E);
  float P3e = fexp2(acc3.x * -TWO_LOG2E);
  float P3o = fexp2(acc3.y * -TWO_LOG2E);
  float s0 = P0e + P0o, s1 = P1e + P1o, s2 = P2e + P2o, s3 = P3e + P3o;
#pragma unroll
  for (int off = 32; off > 0; off >>= 1) {
    s0 += __shfl_xor(s0, off);
    s1 += __shfl_xor(s1, off);
    s2 += __shfl_xor(s2, off);
    s3 += __shfl_xor(s3, off);
  }
  if (lane == 0) {
    red[wav][0] = s0; red[wav][1] = s1; red[wav][2] = s2; red[wav][3] = s3;
  }
  __syncthreads();
  const int rb = hgrp * 4;
  float r0 = frcp(red[rb][0] + red[rb + 1][0] + red[rb + 2][0] + red[rb + 3][0]);
  float r1 = frcp(red[rb][1] + red[rb + 1][1] + red[rb + 2][1] + red[rb + 3][1]);
  float r2 = frcp(red[rb][2] + red[rb + 1][2] + red[rb + 2][2] + red[rb + 3][2]);
  float r3 = frcp(red[rb][3] + red[rb + 1][3] + red[rb + 2][3] + red[rb + 3][3]);

  const int row0 = (b * 512 + qbase) * 512;
  const int k0 = kidx * 2;
  if (hgrp == 0) {
    *(float2*)&attn[row0 + k0] = make_float2(P0e * r0, P0o * r0);
    *(float2*)&attn[row0 + 512 + k0] = make_float2(P1e * r1, P1o * r1);
  } else {
    *(float2*)&attn[row0 + 1024 + k0] = make_float2(P2e * r2, P2o * r2);
    *(float2*)&attn[row0 + 1536 + k0] = make_float2(P3e * r3, P3o * r3);
  }
}

// ---------------------------------------------------------------------------
// K3: context[b] = attn[b] @ value[b] via bf16 MFMA 16x16x32.
// RETILED: 64m x 32n, BK=64 -> grid (16,8,8) = 1024 blocks = 4 blocks/CU
// (was 2; K3 was latency-bound at 2 waves/SIMD). 4 waves (2x2), wave tile
// 32m x 16n (2 m-frags). LDS 12KB.
// ---------------------------------------------------------------------------
__global__ __launch_bounds__(256) void k_context_mfma(
    const float* __restrict__ attn, const unsigned short* __restrict__ valT,
    float* __restrict__ ctx) {
  __shared__ __align__(16) char At[64 * 128];  // [m][k] bf16 swizzled, 8KB
  __shared__ __align__(16) char Bt[32 * 128];  // [n][k] bf16 swizzled, 4KB

  const int t = threadIdx.x;
  const int b = blockIdx.z;
  const int m0 = blockIdx.y * 64, n0 = blockIdx.x * 32;
  const int w = t >> 6, l = t & 63;
  const int wr = w >> 1, wc = w & 1;

  f32x4v acc[2];
  acc[0] = 0;
  acc[1] = 0;

  const int sr = t >> 2;        // A staging row 0..63
  const int sg = (t & 3);       // A granule base
  const int sswz = sr & 7;
  const int rbs = t >> 3;       // B staging row 0..31
  const int gbs = t & 7;        // B granule

  for (int k0 = 0; k0 < 512; k0 += 64) {
    if (k0) __syncthreads();
    {  // stage A: 16 f32 -> 16 bf16 per thread (64 rows x 8 granules)
      const float* src = &attn[(b * 512 + m0 + sr) * 512 + k0 + sg * 16];
      char* dst = At + sr * 128;
#pragma unroll
      for (int h = 0; h < 2; ++h) {
        float4 f0 = *(const float4*)(src + h * 8);
        float4 f1 = *(const float4*)(src + h * 8 + 4);
        uint4 p = make_uint4(pack2bf(f0.x, f0.y), pack2bf(f0.z, f0.w),
                             pack2bf(f1.x, f1.y), pack2bf(f1.z, f1.w));
        int g = sg * 2 + h;
        *(uint4*)(dst + ((g ^ sswz) << 4)) = p;
      }
      // stage B^T: 32 rows x 8 granules = 256 slots, one uint4 per thread
      uint4 vb = *(const uint4*)&valT[(b * 512 + n0 + rbs) * 512 + k0 + gbs * 8];
      *(uint4*)(Bt + rbs * 128 + ((gbs ^ (rbs & 7)) << 4)) = vb;
    }
    __syncthreads();
#pragma unroll
    for (int ks = 0; ks < 2; ++ks) {
      const int gb = ks * 4 + (l >> 4);
      const int rb = wc * 16 + (l & 15);
      short8 bf_ = *(const short8*)(Bt + rb * 128 + ((gb ^ (rb & 7)) << 4));
#pragma unroll
      for (int mi = 0; mi < 2; ++mi) {
        int ra = wr * 32 + mi * 16 + (l & 15);
        short8 af = *(const short8*)(At + ra * 128 + ((gb ^ (ra & 7)) << 4));
        acc[mi] = __builtin_amdgcn_mfma_f32_16x16x32_bf16(af, bf_, acc[mi], 0, 0, 0);
      }
    }
  }
  __syncthreads();
#pragma unroll
  for (int mi = 0; mi < 2; ++mi) {
    int col = n0 + wc * 16 + (l & 15);
#pragma unroll
    for (int j = 0; j < 4; ++j) {
      int row = m0 + wr * 32 + mi * 16 + (l >> 4) * 4 + j;
      ctx[(b * 512 + row) * 512 + col] = acc[mi][j];
    }
  }
}

extern "C" void kernel_launch(void* const* d_in, const int* in_sizes, int n_in,
                              void* d_out, int out_size, void* d_ws, size_t ws_size,
                              hipStream_t stream) {
  const float* query = (const float*)d_in[0];
  const float* key   = (const float*)d_in[1];
  const float* value = (const float*)d_in[2];
  const float* w1    = (const float*)d_in[3];
  const float* w2    = (const float*)d_in[4];
  const float* v     = (const float*)d_in[5];

  float* attn = (float*)d_out;
  float* ctx  = attn + 8 * 512 * 512;

  float* Aexp = (float*)d_ws;                                    // 4096*128 f32
  unsigned short* BexpT = (unsigned short*)(Aexp + 4096 * 128);  // 128*4096 bf16
  unsigned short* valT = BexpT + 128 * 4096;                     // 8*512*512 bf16

  k_pre<<<dim3(512, 2), 256, 0, stream>>>(query, key, w1, w2, value,
                                          Aexp, BexpT, valT);
  k_score_softmax<<<dim3(128, 8), 512, 0, stream>>>(Aexp, BexpT, v, attn);
  k_context_mfma<<<dim3(16, 8, 8), 256, 0, stream>>>(attn, valT, ctx);
}

// Round 19
// 52.210 us; speedup vs baseline: 1.1996x; 1.1133x over previous
//
#include <hip/hip_runtime.h>

#define TWO_LOG2E 2.8853900817779268f

__device__ __forceinline__ float frcp(float x) {
#if __has_builtin(__builtin_amdgcn_rcpf)
  return __builtin_amdgcn_rcpf(x);
#else
  return 1.0f / x;
#endif
}
__device__ __forceinline__ float fexp2(float x) {
#if __has_builtin(__builtin_amdgcn_exp2f)
  return __builtin_amdgcn_exp2f(x);
#else
  return exp2f(x);
#endif
}
__device__ __forceinline__ unsigned short f2bf(float f) {  // RNE f32->bf16
  unsigned int u = __float_as_uint(f);
  u += 0x7fffu + ((u >> 16) & 1u);
  return (unsigned short)(u >> 16);
}
__device__ __forceinline__ unsigned int pack2bf(float lo, float hi) {
  return (unsigned int)f2bf(lo) | ((unsigned int)f2bf(hi) << 16);
}

using short8 = __attribute__((ext_vector_type(8))) short;
using f32x4v = __attribute__((ext_vector_type(4))) float;
using f32x8s = __attribute__((ext_vector_type(8))) float;
using f32x2 = __attribute__((ext_vector_type(2))) float;

__device__ __forceinline__ f32x2 pkfma(f32x2 a, f32x2 b, f32x2 c) {
  return __builtin_elementwise_fma(a, b, c);
}
__device__ __forceinline__ f32x2 splat2(float x) {
  f32x2 r;
  r.x = x;
  r.y = x;
  return r;
}
__device__ __forceinline__ f32x2 unpack_bf2(unsigned u) {  // (k-even, k-odd)
  f32x2 r;
  r.x = __uint_as_float(u << 16);
  r.y = __uint_as_float(u & 0xffff0000u);
  return r;
}
// s += sum_{i=0..3} v_i/(a_i*b_i+1) for BOTH k-parities, ONE rcp per parity.
__device__ __forceinline__ void cell4k(float a0, float a1, float a2, float a3,
                                       f32x2 b0, f32x2 b1, f32x2 b2, f32x2 b3,
                                       float v0, float v1, float v2, float v3,
                                       f32x2& s) {
  const f32x2 one = {1.f, 1.f};
  f32x2 x0 = pkfma(splat2(a0), b0, one);
  f32x2 x1 = pkfma(splat2(a1), b1, one);
  f32x2 x2 = pkfma(splat2(a2), b2, one);
  f32x2 x3 = pkfma(splat2(a3), b3, one);
  f32x2 p01 = x0 * x1, p23 = x2 * x3;
  f32x2 n01 = pkfma(splat2(v0), x1, splat2(v1) * x0);
  f32x2 n23 = pkfma(splat2(v2), x3, splat2(v3) * x2);
  f32x2 num = pkfma(n01, p23, n23 * p01);
  f32x2 den = p01 * p23;
  f32x2 r;
  r.x = frcp(den.x);
  r.y = frcp(den.y);
  s = pkfma(num, r, s);
}

// ---------------------------------------------------------------------------
// k_pre: fused projections + value transpose (r12, unchanged).
// ---------------------------------------------------------------------------
__global__ __launch_bounds__(256) void k_pre(
    const float* __restrict__ query, const float* __restrict__ key,
    const float* __restrict__ w1, const float* __restrict__ w2,
    const float* __restrict__ value,
    float* __restrict__ Aout, unsigned short* __restrict__ BoutT,
    unsigned short* __restrict__ valT) {
  __shared__ __align__(16) char Abuf[16 * 128];   // [m][k] bf16, swizzled
  __shared__ __align__(16) char Bbuf[128 * 128];  // [n][k] bf16, swizzled
  __shared__ unsigned short ts[64][66];           // valT transpose buffer

  const int t = threadIdx.x;

  if (blockIdx.y == 0) {  // ---- projections ----
    const int px = blockIdx.x;
    const bool isB = px >= 256;
    const float* in = isB ? key : query;
    const float* wm = isB ? w2 : w1;
    const int m0g = (px & 255) * 16;
    const int w = t >> 6, l = t & 63;

    f32x4v acc[2];
    acc[0] = 0;
    acc[1] = 0;

    float4 aS;
    float4 wS[4][2];

#define P_LOAD(k0_)                                                        \
  {                                                                        \
    aS = *(const float4*)&in[(m0g + (t >> 4)) * 512 + (k0_) + (t & 15) * 4]; \
    _Pragma("unroll") for (int i = 0; i < 4; ++i) {                        \
      int tt = t + i * 256;                                                \
      int row = tt >> 3, g = tt & 7;                                       \
      const float* src = &wm[row * 512 + (k0_) + g * 8];                   \
      wS[i][0] = *(const float4*)src;                                      \
      wS[i][1] = *(const float4*)(src + 4);                                \
    }                                                                      \
  }
#define P_WRITE()                                                          \
  {                                                                        \
    int arow = t >> 4, q4 = t & 15;                                        \
    *(uint2*)(Abuf + arow * 128 + (((q4 >> 1) ^ (arow & 7)) << 4) +        \
              ((q4 & 1) << 3)) =                                           \
        make_uint2(pack2bf(aS.x, aS.y), pack2bf(aS.z, aS.w));              \
    _Pragma("unroll") for (int i = 0; i < 4; ++i) {                        \
      int tt = t + i * 256;                                                \
      int row = tt >> 3, g = tt & 7;                                       \
      uint4 p = make_uint4(                                                \
          pack2bf(wS[i][0].x, wS[i][0].y), pack2bf(wS[i][0].z, wS[i][0].w),\
          pack2bf(wS[i][1].x, wS[i][1].y), pack2bf(wS[i][1].z, wS[i][1].w));\
      *(uint4*)(Bbuf + row * 128 + ((g ^ (row & 7)) << 4)) = p;            \
    }                                                                      \
  }

    P_LOAD(0);
#pragma unroll
    for (int ks8 = 0; ks8 < 8; ++ks8) {
      if (ks8) __syncthreads();
      P_WRITE();
      if (ks8 < 7) P_LOAD(ks8 * 64 + 64);
      __syncthreads();
#pragma unroll
      for (int ks = 0; ks < 2; ++ks) {
        const int gb = ks * 4 + (l >> 4);
        const int ra = l & 15;
        short8 af = *(const short8*)(Abuf + ra * 128 + ((gb ^ (ra & 7)) << 4));
#pragma unroll
        for (int ni = 0; ni < 2; ++ni) {
          const int rb = w * 32 + ni * 16 + (l & 15);
          short8 bf_ = *(const short8*)(Bbuf + rb * 128 + ((gb ^ (rb & 7)) << 4));
          if (isB)
            acc[ni] = __builtin_amdgcn_mfma_f32_16x16x32_bf16(bf_, af, acc[ni], 0, 0, 0);
          else
            acc[ni] = __builtin_amdgcn_mfma_f32_16x16x32_bf16(af, bf_, acc[ni], 0, 0, 0);
        }
      }
    }
#undef P_LOAD
#undef P_WRITE
    if (!isB) {
#pragma unroll
      for (int ni = 0; ni < 2; ++ni) {
        int col = w * 32 + ni * 16 + (l & 15);  // h
#pragma unroll
        for (int j = 0; j < 4; ++j) {
          int row = m0g + (l >> 4) * 4 + j;  // m
          Aout[row * 128 + col] = fexp2(acc[ni][j] * TWO_LOG2E);
        }
      }
    } else {
      int m = m0g + (l & 15);  // contiguous across lanes
#pragma unroll
      for (int ni = 0; ni < 2; ++ni)
#pragma unroll
        for (int j = 0; j < 4; ++j) {
          int h = w * 32 + ni * 16 + (l >> 4) * 4 + j;
          BoutT[h * 4096 + m] = f2bf(fexp2(acc[ni][j] * TWO_LOG2E));
        }
    }
  } else {  // ---- valT ----
    const int x = blockIdx.x;
    const int b = x >> 6, k0 = ((x >> 3) & 7) * 64, n0 = (x & 7) * 64;
    {
      int kr = t >> 4, n4 = (t & 15) * 4;
#pragma unroll
      for (int i = 0; i < 4; ++i) {
        float4 f =
            *(const float4*)&value[((b * 512) + k0 + kr + 16 * i) * 512 + n0 + n4];
        *(ushort4*)&ts[kr + 16 * i][n4] =
            make_ushort4(f2bf(f.x), f2bf(f.y), f2bf(f.z), f2bf(f.w));
      }
    }
    __syncthreads();
    {
      int nw = t >> 4, k4 = (t & 15) * 4;
#pragma unroll
      for (int i = 0; i < 4; ++i) {
        int n = nw + 16 * i;
        ushort4 o = make_ushort4(ts[k4 + 0][n], ts[k4 + 1][n], ts[k4 + 2][n],
                                 ts[k4 + 3][n]);
        *(ushort4*)&valT[((b * 512) + n0 + n) * 512 + k0 + k4] = o;
      }
    }
  }
}

// ---------------------------------------------------------------------------
// K2: (r17 structure) + bf16 attn side-channel write for K3 (same rounding
// K3 used to apply in staging; f32 d_out path unchanged).
// ---------------------------------------------------------------------------
__global__ __launch_bounds__(512, 8) void k_score_softmax(
    const float* __restrict__ Aexp, const unsigned short* __restrict__ BexpT,
    const float* __restrict__ vw, float* __restrict__ attn,
    unsigned short* __restrict__ attnBf) {
  __shared__ __align__(16) f32x2 part[512][4];  // 16KB partial-S exchange
  __shared__ float red[8][4];

  const int tid = threadIdx.x;
  const int b = blockIdx.y;
  const int qbase = blockIdx.x * 4;
  const int wav = tid >> 6;
  const int hgrp = wav >> 2;  // h-half 0/1
  const int kq = wav & 3;     // k-quarter
  const int lane = tid & 63;

  const unsigned* const bbase32 = (const unsigned*)(BexpT + b * 512);
  const int kidx = kq * 64 + lane;  // dword index within a k-row

  const float* const pa0 =
      Aexp + __builtin_amdgcn_readfirstlane((b * 512 + qbase) * 128);
  const float* const pa1 = pa0 + 128;
  const float* const pa2 = pa0 + 256;
  const float* const pa3 = pa0 + 384;
  const float* const pv = vw;
  const unsigned hoff = (unsigned)__builtin_amdgcn_readfirstlane(hgrp * 256);

  f32x2 acc0 = {0.f, 0.f}, acc1 = {0.f, 0.f};
  f32x2 acc2 = {0.f, 0.f}, acc3 = {0.f, 0.f};

#pragma unroll
  for (int ch = 0; ch < 8; ++ch) {  // 8 chunks x 8 h (this h-half)
    f32x8s sa0, sa1, sa2, sa3, sv;
    unsigned soff = hoff + (unsigned)(ch * 32);
    asm volatile(
        "s_load_dwordx8 %0, %5, %10\n\t"
        "s_load_dwordx8 %1, %6, %10\n\t"
        "s_load_dwordx8 %2, %7, %10\n\t"
        "s_load_dwordx8 %3, %8, %10\n\t"
        "s_load_dwordx8 %4, %9, %10"
        : "=&s"(sa0), "=&s"(sa1), "=&s"(sa2), "=&s"(sa3), "=&s"(sv)
        : "s"(pa0), "s"(pa1), "s"(pa2), "s"(pa3), "s"(pv), "s"(soff));

    unsigned u[8];
#pragma unroll
    for (int j = 0; j < 8; ++j)
      u[j] = bbase32[hgrp * 131072 + ch * 16384 + j * 2048 + kidx];

    asm volatile("s_waitcnt lgkmcnt(0)"
                 : "+s"(sa0), "+s"(sa1), "+s"(sa2), "+s"(sa3), "+s"(sv));

#pragma unroll
    for (int g = 0; g < 2; ++g) {
      f32x2 b0 = unpack_bf2(u[g * 4 + 0]);
      f32x2 b1 = unpack_bf2(u[g * 4 + 1]);
      f32x2 b2 = unpack_bf2(u[g * 4 + 2]);
      f32x2 b3 = unpack_bf2(u[g * 4 + 3]);
      const int h = g * 4;
      cell4k(sa0[h], sa0[h + 1], sa0[h + 2], sa0[h + 3], b0, b1, b2, b3,
             sv[h], sv[h + 1], sv[h + 2], sv[h + 3], acc0);
      cell4k(sa1[h], sa1[h + 1], sa1[h + 2], sa1[h + 3], b0, b1, b2, b3,
             sv[h], sv[h + 1], sv[h + 2], sv[h + 3], acc1);
      cell4k(sa2[h], sa2[h + 1], sa2[h + 2], sa2[h + 3], b0, b1, b2, b3,
             sv[h], sv[h + 1], sv[h + 2], sv[h + 3], acc2);
      cell4k(sa3[h], sa3[h + 1], sa3[h + 2], sa3[h + 3], b0, b1, b2, b3,
             sv[h], sv[h + 1], sv[h + 2], sv[h + 3], acc3);
    }
  }

  part[tid][0] = acc0;
  part[tid][1] = acc1;
  part[tid][2] = acc2;
  part[tid][3] = acc3;
  __syncthreads();
  {
    const f32x2* pp = part[tid ^ 256];
    acc0 += pp[0];
    acc1 += pp[1];
    acc2 += pp[2];
    acc3 += pp[3];
  }

  float P0e = fexp2(acc0.x * -TWO_LOG2E);
  float P0o = fexp2(acc0.y * -TWO_LOG2E);
  float P1e = fexp2(acc1.x * -TWO_LOG2E);
  float P1o = fexp2(acc1.y * -TWO_LOG2E);
  float P2e = fexp2(acc2.x * -TWO_LOG2E);
  float P2o = fexp2(acc2.y * -TWO_LOG2E);
  float P3e = fexp2(acc3.x * -TWO_LOG2E);
  float P3o = fexp2(acc3.y * -TWO_LOG2E);
  float s0 = P0e + P0o, s1 = P1e + P1o, s2 = P2e + P2o, s3 = P3e + P3o;
#pragma unroll
  for (int off = 32; off > 0; off >>= 1) {
    s0 += __shfl_xor(s0, off);
    s1 += __shfl_xor(s1, off);
    s2 += __shfl_xor(s2, off);
    s3 += __shfl_xor(s3, off);
  }
  if (lane == 0) {
    red[wav][0] = s0; red[wav][1] = s1; red[wav][2] = s2; red[wav][3] = s3;
  }
  __syncthreads();
  const int rb = hgrp * 4;
  float r0 = frcp(red[rb][0] + red[rb + 1][0] + red[rb + 2][0] + red[rb + 3][0]);
  float r1 = frcp(red[rb][1] + red[rb + 1][1] + red[rb + 2][1] + red[rb + 3][1]);
  float r2 = frcp(red[rb][2] + red[rb + 1][2] + red[rb + 2][2] + red[rb + 3][2]);
  float r3 = frcp(red[rb][3] + red[rb + 1][3] + red[rb + 2][3] + red[rb + 3][3]);

  const int row0 = (b * 512 + qbase) * 512;
  const int k0 = kidx * 2;
  if (hgrp == 0) {
    float a0e = P0e * r0, a0o = P0o * r0, a1e = P1e * r1, a1o = P1o * r1;
    *(float2*)&attn[row0 + k0] = make_float2(a0e, a0o);
    *(float2*)&attn[row0 + 512 + k0] = make_float2(a1e, a1o);
    *(unsigned*)&attnBf[row0 + k0] = pack2bf(a0e, a0o);
    *(unsigned*)&attnBf[row0 + 512 + k0] = pack2bf(a1e, a1o);
  } else {
    float a2e = P2e * r2, a2o = P2o * r2, a3e = P3e * r3, a3o = P3o * r3;
    *(float2*)&attn[row0 + 1024 + k0] = make_float2(a2e, a2o);
    *(float2*)&attn[row0 + 1536 + k0] = make_float2(a3e, a3o);
    *(unsigned*)&attnBf[row0 + 1024 + k0] = pack2bf(a2e, a2o);
    *(unsigned*)&attnBf[row0 + 1536 + k0] = pack2bf(a3e, a3o);
  }
}

// ---------------------------------------------------------------------------
// K3: context[b] = attnBf @ valT via bf16 MFMA 16x16x32. 64m x 32n, BK=64,
// grid (16,8,8) = 4 blocks/CU. A now pre-packed bf16 (side-channel from K2):
// staging is a pure uint4 copy on both operands.
// ---------------------------------------------------------------------------
__global__ __launch_bounds__(256) void k_context_mfma(
    const unsigned short* __restrict__ attnBf,
    const unsigned short* __restrict__ valT, float* __restrict__ ctx) {
  __shared__ __align__(16) char At[64 * 128];  // [m][k] bf16 swizzled, 8KB
  __shared__ __align__(16) char Bt[32 * 128];  // [n][k] bf16 swizzled, 4KB

  const int t = threadIdx.x;
  const int b = blockIdx.z;
  const int m0 = blockIdx.y * 64, n0 = blockIdx.x * 32;
  const int w = t >> 6, l = t & 63;
  const int wr = w >> 1, wc = w & 1;

  f32x4v acc[2];
  acc[0] = 0;
  acc[1] = 0;

  const int sr = t >> 2;        // A staging row 0..63
  const int sg = (t & 3);       // A granule base (2 granules/thread)
  const int sswz = sr & 7;
  const int rbs = t >> 3;       // B staging row 0..31
  const int gbs = t & 7;        // B granule

  for (int k0 = 0; k0 < 512; k0 += 64) {
    if (k0) __syncthreads();
    {  // stage A: pure bf16 copy, 2 x uint4 per thread
      const unsigned short* srca = &attnBf[(b * 512 + m0 + sr) * 512 + k0];
      char* dst = At + sr * 128;
#pragma unroll
      for (int h = 0; h < 2; ++h) {
        int g = sg * 2 + h;
        uint4 va = *(const uint4*)(srca + g * 8);
        *(uint4*)(dst + ((g ^ sswz) << 4)) = va;
      }
      // stage B^T: 32 rows x 8 granules, one uint4 per thread
      uint4 vb = *(const uint4*)&valT[(b * 512 + n0 + rbs) * 512 + k0 + gbs * 8];
      *(uint4*)(Bt + rbs * 128 + ((gbs ^ (rbs & 7)) << 4)) = vb;
    }
    __syncthreads();
#pragma unroll
    for (int ks = 0; ks < 2; ++ks) {
      const int gb = ks * 4 + (l >> 4);
      const int rb = wc * 16 + (l & 15);
      short8 bf_ = *(const short8*)(Bt + rb * 128 + ((gb ^ (rb & 7)) << 4));
#pragma unroll
      for (int mi = 0; mi < 2; ++mi) {
        int ra = wr * 32 + mi * 16 + (l & 15);
        short8 af = *(const short8*)(At + ra * 128 + ((gb ^ (ra & 7)) << 4));
        acc[mi] = __builtin_amdgcn_mfma_f32_16x16x32_bf16(af, bf_, acc[mi], 0, 0, 0);
      }
    }
  }
  __syncthreads();
#pragma unroll
  for (int mi = 0; mi < 2; ++mi) {
    int col = n0 + wc * 16 + (l & 15);
#pragma unroll
    for (int j = 0; j < 4; ++j) {
      int row = m0 + wr * 32 + mi * 16 + (l >> 4) * 4 + j;
      ctx[(b * 512 + row) * 512 + col] = acc[mi][j];
    }
  }
}

extern "C" void kernel_launch(void* const* d_in, const int* in_sizes, int n_in,
                              void* d_out, int out_size, void* d_ws, size_t ws_size,
                              hipStream_t stream) {
  const float* query = (const float*)d_in[0];
  const float* key   = (const float*)d_in[1];
  const float* value = (const float*)d_in[2];
  const float* w1    = (const float*)d_in[3];
  const float* w2    = (const float*)d_in[4];
  const float* v     = (const float*)d_in[5];

  float* attn = (float*)d_out;
  float* ctx  = attn + 8 * 512 * 512;

  float* Aexp = (float*)d_ws;                                    // 2MB
  unsigned short* BexpT = (unsigned short*)(Aexp + 4096 * 128);  // 1MB
  unsigned short* valT = BexpT + 128 * 4096;                     // 4MB
  unsigned short* attnBf = valT + 8 * 512 * 512;                 // 4MB (11MB tot)

  k_pre<<<dim3(512, 2), 256, 0, stream>>>(query, key, w1, w2, value,
                                          Aexp, BexpT, valT);
  k_score_softmax<<<dim3(128, 8), 512, 0, stream>>>(Aexp, BexpT, v, attn, attnBf);
  k_context_mfma<<<dim3(16, 8, 8), 256, 0, stream>>>(attnBf, valT, ctx);
}

// Round 20
// 51.861 us; speedup vs baseline: 1.2077x; 1.0067x over previous
//
#include <hip/hip_runtime.h>

#define TWO_LOG2E 2.8853900817779268f

__device__ __forceinline__ float frcp(float x) {
#if __has_builtin(__builtin_amdgcn_rcpf)
  return __builtin_amdgcn_rcpf(x);
#else
  return 1.0f / x;
#endif
}
__device__ __forceinline__ float fexp2(float x) {
#if __has_builtin(__builtin_amdgcn_exp2f)
  return __builtin_amdgcn_exp2f(x);
#else
  return exp2f(x);
#endif
}
__device__ __forceinline__ unsigned short f2bf(float f) {  // RNE f32->bf16
  unsigned int u = __float_as_uint(f);
  u += 0x7fffu + ((u >> 16) & 1u);
  return (unsigned short)(u >> 16);
}
__device__ __forceinline__ unsigned int pack2bf(float lo, float hi) {
  return (unsigned int)f2bf(lo) | ((unsigned int)f2bf(hi) << 16);
}

using short8 = __attribute__((ext_vector_type(8))) short;
using f32x4v = __attribute__((ext_vector_type(4))) float;
using f32x8s = __attribute__((ext_vector_type(8))) float;
using f32x2 = __attribute__((ext_vector_type(2))) float;

__device__ __forceinline__ f32x2 pkfma(f32x2 a, f32x2 b, f32x2 c) {
  return __builtin_elementwise_fma(a, b, c);
}
__device__ __forceinline__ f32x2 splat2(float x) {
  f32x2 r;
  r.x = x;
  r.y = x;
  return r;
}
__device__ __forceinline__ f32x2 unpack_bf2(unsigned u) {  // (k-even, k-odd)
  f32x2 r;
  r.x = __uint_as_float(u << 16);
  r.y = __uint_as_float(u & 0xffff0000u);
  return r;
}
// s += sum_{i=0..3} v_i/(a_i*b_i+1) for BOTH k-parities, ONE rcp per parity.
__device__ __forceinline__ void cell4k(float a0, float a1, float a2, float a3,
                                       f32x2 b0, f32x2 b1, f32x2 b2, f32x2 b3,
                                       float v0, float v1, float v2, float v3,
                                       f32x2& s) {
  const f32x2 one = {1.f, 1.f};
  f32x2 x0 = pkfma(splat2(a0), b0, one);
  f32x2 x1 = pkfma(splat2(a1), b1, one);
  f32x2 x2 = pkfma(splat2(a2), b2, one);
  f32x2 x3 = pkfma(splat2(a3), b3, one);
  f32x2 p01 = x0 * x1, p23 = x2 * x3;
  f32x2 n01 = pkfma(splat2(v0), x1, splat2(v1) * x0);
  f32x2 n23 = pkfma(splat2(v2), x3, splat2(v3) * x2);
  f32x2 num = pkfma(n01, p23, n23 * p01);
  f32x2 den = p01 * p23;
  f32x2 r;
  r.x = frcp(den.x);
  r.y = frcp(den.y);
  s = pkfma(num, r, s);
}

// ---------------------------------------------------------------------------
// k_pre: fused projections + value transpose (r12, unchanged).
// ---------------------------------------------------------------------------
__global__ __launch_bounds__(256) void k_pre(
    const float* __restrict__ query, const float* __restrict__ key,
    const float* __restrict__ w1, const float* __restrict__ w2,
    const float* __restrict__ value,
    float* __restrict__ Aout, unsigned short* __restrict__ BoutT,
    unsigned short* __restrict__ valT) {
  __shared__ __align__(16) char Abuf[16 * 128];   // [m][k] bf16, swizzled
  __shared__ __align__(16) char Bbuf[128 * 128];  // [n][k] bf16, swizzled
  __shared__ unsigned short ts[64][66];           // valT transpose buffer

  const int t = threadIdx.x;

  if (blockIdx.y == 0) {  // ---- projections ----
    const int px = blockIdx.x;
    const bool isB = px >= 256;
    const float* in = isB ? key : query;
    const float* wm = isB ? w2 : w1;
    const int m0g = (px & 255) * 16;
    const int w = t >> 6, l = t & 63;

    f32x4v acc[2];
    acc[0] = 0;
    acc[1] = 0;

    float4 aS;
    float4 wS[4][2];

#define P_LOAD(k0_)                                                        \
  {                                                                        \
    aS = *(const float4*)&in[(m0g + (t >> 4)) * 512 + (k0_) + (t & 15) * 4]; \
    _Pragma("unroll") for (int i = 0; i < 4; ++i) {                        \
      int tt = t + i * 256;                                                \
      int row = tt >> 3, g = tt & 7;                                       \
      const float* src = &wm[row * 512 + (k0_) + g * 8];                   \
      wS[i][0] = *(const float4*)src;                                      \
      wS[i][1] = *(const float4*)(src + 4);                                \
    }                                                                      \
  }
#define P_WRITE()                                                          \
  {                                                                        \
    int arow = t >> 4, q4 = t & 15;                                        \
    *(uint2*)(Abuf + arow * 128 + (((q4 >> 1) ^ (arow & 7)) << 4) +        \
              ((q4 & 1) << 3)) =                                           \
        make_uint2(pack2bf(aS.x, aS.y), pack2bf(aS.z, aS.w));              \
    _Pragma("unroll") for (int i = 0; i < 4; ++i) {                        \
      int tt = t + i * 256;                                                \
      int row = tt >> 3, g = tt & 7;                                       \
      uint4 p = make_uint4(                                                \
          pack2bf(wS[i][0].x, wS[i][0].y), pack2bf(wS[i][0].z, wS[i][0].w),\
          pack2bf(wS[i][1].x, wS[i][1].y), pack2bf(wS[i][1].z, wS[i][1].w));\
      *(uint4*)(Bbuf + row * 128 + ((g ^ (row & 7)) << 4)) = p;            \
    }                                                                      \
  }

    P_LOAD(0);
#pragma unroll
    for (int ks8 = 0; ks8 < 8; ++ks8) {
      if (ks8) __syncthreads();
      P_WRITE();
      if (ks8 < 7) P_LOAD(ks8 * 64 + 64);
      __syncthreads();
#pragma unroll
      for (int ks = 0; ks < 2; ++ks) {
        const int gb = ks * 4 + (l >> 4);
        const int ra = l & 15;
        short8 af = *(const short8*)(Abuf + ra * 128 + ((gb ^ (ra & 7)) << 4));
#pragma unroll
        for (int ni = 0; ni < 2; ++ni) {
          const int rb = w * 32 + ni * 16 + (l & 15);
          short8 bf_ = *(const short8*)(Bbuf + rb * 128 + ((gb ^ (rb & 7)) << 4));
          if (isB)
            acc[ni] = __builtin_amdgcn_mfma_f32_16x16x32_bf16(bf_, af, acc[ni], 0, 0, 0);
          else
            acc[ni] = __builtin_amdgcn_mfma_f32_16x16x32_bf16(af, bf_, acc[ni], 0, 0, 0);
        }
      }
    }
#undef P_LOAD
#undef P_WRITE
    if (!isB) {
#pragma unroll
      for (int ni = 0; ni < 2; ++ni) {
        int col = w * 32 + ni * 16 + (l & 15);  // h
#pragma unroll
        for (int j = 0; j < 4; ++j) {
          int row = m0g + (l >> 4) * 4 + j;  // m
          Aout[row * 128 + col] = fexp2(acc[ni][j] * TWO_LOG2E);
        }
      }
    } else {
      int m = m0g + (l & 15);  // contiguous across lanes
#pragma unroll
      for (int ni = 0; ni < 2; ++ni)
#pragma unroll
        for (int j = 0; j < 4; ++j) {
          int h = w * 32 + ni * 16 + (l >> 4) * 4 + j;
          BoutT[h * 4096 + m] = f2bf(fexp2(acc[ni][j] * TWO_LOG2E));
        }
    }
  } else {  // ---- valT ----
    const int x = blockIdx.x;
    const int b = x >> 6, k0 = ((x >> 3) & 7) * 64, n0 = (x & 7) * 64;
    {
      int kr = t >> 4, n4 = (t & 15) * 4;
#pragma unroll
      for (int i = 0; i < 4; ++i) {
        float4 f =
            *(const float4*)&value[((b * 512) + k0 + kr + 16 * i) * 512 + n0 + n4];
        *(ushort4*)&ts[kr + 16 * i][n4] =
            make_ushort4(f2bf(f.x), f2bf(f.y), f2bf(f.z), f2bf(f.w));
      }
    }
    __syncthreads();
    {
      int nw = t >> 4, k4 = (t & 15) * 4;
#pragma unroll
      for (int i = 0; i < 4; ++i) {
        int n = nw + 16 * i;
        ushort4 o = make_ushort4(ts[k4 + 0][n], ts[k4 + 1][n], ts[k4 + 2][n],
                                 ts[k4 + 3][n]);
        *(ushort4*)&valT[((b * 512) + n0 + n) * 512 + k0 + k4] = o;
      }
    }
  }
}

// ---------------------------------------------------------------------------
// K2: S[q,k] = sum_h v[h]/(A[q,h]*B[k,h]+1);  attn = softmax_k(-2S).
// 8 q-rows/block (each B dword + unpack + SMEM batch feeds 16 cells), 512
// threads = 8 waves, h-split (waves 0-3: h<64, 4-7: h>=64; h-half folded into
// the SMEM BASE via readfirstlane, offsets pure "i" immediates). Partials
// combined via 32KB LDS exchange (tid^256). bf16 attn side-channel for K3.
// No min-pass. grid (64,8) = 2 blocks/CU, 4 waves/SIMD (r17: TLP not binding).
// ---------------------------------------------------------------------------
__global__ __launch_bounds__(512, 4) void k_score_softmax(
    const float* __restrict__ Aexp, const unsigned short* __restrict__ BexpT,
    const float* __restrict__ vw, float* __restrict__ attn,
    unsigned short* __restrict__ attnBf) {
  __shared__ __align__(16) f32x2 part[512][8];  // 32KB partial-S exchange
  __shared__ float red[8][8];

  const int tid = threadIdx.x;
  const int b = blockIdx.y;
  const int qbase = blockIdx.x * 8;
  const int wav = tid >> 6;
  const int hgrp = wav >> 2;  // h-half 0/1
  const int kq = wav & 3;     // k-quarter
  const int lane = tid & 63;

  const unsigned* const bbase32 = (const unsigned*)(BexpT + b * 512);
  const int kidx = kq * 64 + lane;  // dword index within a k-row
  const int hbase = hgrp * 131072;  // dword offset of this h-half in BexpT rows

  // wave-uniform SMEM bases: h-half folded in (readfirstlane -> SGPR).
  const float* const pah =
      Aexp + __builtin_amdgcn_readfirstlane((b * 512 + qbase) * 128 + hgrp * 64);
  const float* const pvh = vw + __builtin_amdgcn_readfirstlane(hgrp * 64);

  f32x2 c0 = {0.f, 0.f}, c1 = {0.f, 0.f}, c2 = {0.f, 0.f}, c3 = {0.f, 0.f};
  f32x2 c4 = {0.f, 0.f}, c5 = {0.f, 0.f}, c6 = {0.f, 0.f}, c7 = {0.f, 0.f};

#define K2_CHUNK(CH_)                                                      \
  {                                                                        \
    f32x8s sa0, sa1, sa2, sa3, sa4, sa5, sa6, sa7, sv;                     \
    asm volatile(                                                          \
        "s_load_dwordx8 %0, %9, %11\n\t"                                   \
        "s_load_dwordx8 %1, %9, %12\n\t"                                   \
        "s_load_dwordx8 %2, %9, %13\n\t"                                   \
        "s_load_dwordx8 %3, %9, %14\n\t"                                   \
        "s_load_dwordx8 %4, %9, %15\n\t"                                   \
        "s_load_dwordx8 %5, %9, %16\n\t"                                   \
        "s_load_dwordx8 %6, %9, %17\n\t"                                   \
        "s_load_dwordx8 %7, %9, %18\n\t"                                   \
        "s_load_dwordx8 %8, %10, %11"                                      \
        : "=&s"(sa0), "=&s"(sa1), "=&s"(sa2), "=&s"(sa3), "=&s"(sa4),      \
          "=&s"(sa5), "=&s"(sa6), "=&s"(sa7), "=&s"(sv)                    \
        : "s"(pah), "s"(pvh), "i"((CH_)*32), "i"((CH_)*32 + 512),          \
          "i"((CH_)*32 + 1024), "i"((CH_)*32 + 1536), "i"((CH_)*32 + 2048),\
          "i"((CH_)*32 + 2560), "i"((CH_)*32 + 3072),                      \
          "i"((CH_)*32 + 3584));                                           \
    unsigned u[8];                                                         \
    _Pragma("unroll") for (int j = 0; j < 8; ++j)                          \
        u[j] = bbase32[hbase + (CH_)*16384 + j * 2048 + kidx];             \
    asm volatile("s_waitcnt lgkmcnt(0)"                                    \
                 : "+s"(sa0), "+s"(sa1), "+s"(sa2), "+s"(sa3), "+s"(sa4),  \
                   "+s"(sa5), "+s"(sa6), "+s"(sa7), "+s"(sv));             \
    _Pragma("unroll") for (int g = 0; g < 2; ++g) {                        \
      f32x2 b0 = unpack_bf2(u[g * 4 + 0]);                                 \
      f32x2 b1 = unpack_bf2(u[g * 4 + 1]);                                 \
      f32x2 b2 = unpack_bf2(u[g * 4 + 2]);                                 \
      f32x2 b3 = unpack_bf2(u[g * 4 + 3]);                                 \
      const int h = g * 4;                                                 \
      cell4k(sa0[h], sa0[h + 1], sa0[h + 2], sa0[h + 3], b0, b1, b2, b3,   \
             sv[h], sv[h + 1], sv[h + 2], sv[h + 3], c0);                  \
      cell4k(sa1[h], sa1[h + 1], sa1[h + 2], sa1[h + 3], b0, b1, b2, b3,   \
             sv[h], sv[h + 1], sv[h + 2], sv[h + 3], c1);                  \
      cell4k(sa2[h], sa2[h + 1], sa2[h + 2], sa2[h + 3], b0, b1, b2, b3,   \
             sv[h], sv[h + 1], sv[h + 2], sv[h + 3], c2);                  \
      cell4k(sa3[h], sa3[h + 1], sa3[h + 2], sa3[h + 3], b0, b1, b2, b3,   \
             sv[h], sv[h + 1], sv[h + 2], sv[h + 3], c3);                  \
      cell4k(sa4[h], sa4[h + 1], sa4[h + 2], sa4[h + 3], b0, b1, b2, b3,   \
             sv[h], sv[h + 1], sv[h + 2], sv[h + 3], c4);                  \
      cell4k(sa5[h], sa5[h + 1], sa5[h + 2], sa5[h + 3], b0, b1, b2, b3,   \
             sv[h], sv[h + 1], sv[h + 2], sv[h + 3], c5);                  \
      cell4k(sa6[h], sa6[h + 1], sa6[h + 2], sa6[h + 3], b0, b1, b2, b3,   \
             sv[h], sv[h + 1], sv[h + 2], sv[h + 3], c6);                  \
      cell4k(sa7[h], sa7[h + 1], sa7[h + 2], sa7[h + 3], b0, b1, b2, b3,   \
             sv[h], sv[h + 1], sv[h + 2], sv[h + 3], c7);                  \
    }                                                                      \
  }

  K2_CHUNK(0)
  K2_CHUNK(1)
  K2_CHUNK(2)
  K2_CHUNK(3)
  K2_CHUNK(4)
  K2_CHUNK(5)
  K2_CHUNK(6)
  K2_CHUNK(7)
#undef K2_CHUNK

  // combine h-halves: partner thread = tid ^ 256 (same q,k; other h-half)
  part[tid][0] = c0; part[tid][1] = c1; part[tid][2] = c2; part[tid][3] = c3;
  part[tid][4] = c4; part[tid][5] = c5; part[tid][6] = c6; part[tid][7] = c7;
  __syncthreads();
  {
    const f32x2* pp = part[tid ^ 256];
    c0 += pp[0]; c1 += pp[1]; c2 += pp[2]; c3 += pp[3];
    c4 += pp[4]; c5 += pp[5]; c6 += pp[6]; c7 += pp[7];
  }

  // attn = exp(-2S)/sum (no max-subtraction: |S|<=sum|v|~9, e^22 safe).
  float P0e = fexp2(c0.x * -TWO_LOG2E), P0o = fexp2(c0.y * -TWO_LOG2E);
  float P1e = fexp2(c1.x * -TWO_LOG2E), P1o = fexp2(c1.y * -TWO_LOG2E);
  float P2e = fexp2(c2.x * -TWO_LOG2E), P2o = fexp2(c2.y * -TWO_LOG2E);
  float P3e = fexp2(c3.x * -TWO_LOG2E), P3o = fexp2(c3.y * -TWO_LOG2E);
  float P4e = fexp2(c4.x * -TWO_LOG2E), P4o = fexp2(c4.y * -TWO_LOG2E);
  float P5e = fexp2(c5.x * -TWO_LOG2E), P5o = fexp2(c5.y * -TWO_LOG2E);
  float P6e = fexp2(c6.x * -TWO_LOG2E), P6o = fexp2(c6.y * -TWO_LOG2E);
  float P7e = fexp2(c7.x * -TWO_LOG2E), P7o = fexp2(c7.y * -TWO_LOG2E);
  float s0 = P0e + P0o, s1 = P1e + P1o, s2 = P2e + P2o, s3 = P3e + P3o;
  float s4 = P4e + P4o, s5 = P5e + P5o, s6 = P6e + P6o, s7 = P7e + P7o;
#pragma unroll
  for (int off = 32; off > 0; off >>= 1) {
    s0 += __shfl_xor(s0, off);
    s1 += __shfl_xor(s1, off);
    s2 += __shfl_xor(s2, off);
    s3 += __shfl_xor(s3, off);
    s4 += __shfl_xor(s4, off);
    s5 += __shfl_xor(s5, off);
    s6 += __shfl_xor(s6, off);
    s7 += __shfl_xor(s7, off);
  }
  if (lane == 0) {
    red[wav][0] = s0; red[wav][1] = s1; red[wav][2] = s2; red[wav][3] = s3;
    red[wav][4] = s4; red[wav][5] = s5; red[wav][6] = s6; red[wav][7] = s7;
  }
  __syncthreads();
  const int rb = hgrp * 4;  // sum this h-group's four k-quarter waves
  const int row0 = (b * 512 + qbase) * 512;
  const int k0 = kidx * 2;
  if (hgrp == 0) {
    float r0 = frcp(red[rb][0] + red[rb + 1][0] + red[rb + 2][0] + red[rb + 3][0]);
    float r1 = frcp(red[rb][1] + red[rb + 1][1] + red[rb + 2][1] + red[rb + 3][1]);
    float r2 = frcp(red[rb][2] + red[rb + 1][2] + red[rb + 2][2] + red[rb + 3][2]);
    float r3 = frcp(red[rb][3] + red[rb + 1][3] + red[rb + 2][3] + red[rb + 3][3]);
    float a0e = P0e * r0, a0o = P0o * r0, a1e = P1e * r1, a1o = P1o * r1;
    float a2e = P2e * r2, a2o = P2o * r2, a3e = P3e * r3, a3o = P3o * r3;
    *(float2*)&attn[row0 + k0] = make_float2(a0e, a0o);
    *(float2*)&attn[row0 + 512 + k0] = make_float2(a1e, a1o);
    *(float2*)&attn[row0 + 1024 + k0] = make_float2(a2e, a2o);
    *(float2*)&attn[row0 + 1536 + k0] = make_float2(a3e, a3o);
    *(unsigned*)&attnBf[row0 + k0] = pack2bf(a0e, a0o);
    *(unsigned*)&attnBf[row0 + 512 + k0] = pack2bf(a1e, a1o);
    *(unsigned*)&attnBf[row0 + 1024 + k0] = pack2bf(a2e, a2o);
    *(unsigned*)&attnBf[row0 + 1536 + k0] = pack2bf(a3e, a3o);
  } else {
    float r4 = frcp(red[rb][4] + red[rb + 1][4] + red[rb + 2][4] + red[rb + 3][4]);
    float r5 = frcp(red[rb][5] + red[rb + 1][5] + red[rb + 2][5] + red[rb + 3][5]);
    float r6 = frcp(red[rb][6] + red[rb + 1][6] + red[rb + 2][6] + red[rb + 3][6]);
    float r7 = frcp(red[rb][7] + red[rb + 1][7] + red[rb + 2][7] + red[rb + 3][7]);
    float a4e = P4e * r4, a4o = P4o * r4, a5e = P5e * r5, a5o = P5o * r5;
    float a6e = P6e * r6, a6o = P6o * r6, a7e = P7e * r7, a7o = P7o * r7;
    *(float2*)&attn[row0 + 2048 + k0] = make_float2(a4e, a4o);
    *(float2*)&attn[row0 + 2560 + k0] = make_float2(a5e, a5o);
    *(float2*)&attn[row0 + 3072 + k0] = make_float2(a6e, a6o);
    *(float2*)&attn[row0 + 3584 + k0] = make_float2(a7e, a7o);
    *(unsigned*)&attnBf[row0 + 2048 + k0] = pack2bf(a4e, a4o);
    *(unsigned*)&attnBf[row0 + 2560 + k0] = pack2bf(a5e, a5o);
    *(unsigned*)&attnBf[row0 + 3072 + k0] = pack2bf(a6e, a6o);
    *(unsigned*)&attnBf[row0 + 3584 + k0] = pack2bf(a7e, a7o);
  }
}

// ---------------------------------------------------------------------------
// K3: context[b] = attnBf @ valT via bf16 MFMA 16x16x32. 64m x 32n, BK=64,
// grid (16,8,8) = 4 blocks/CU. Pure uint4-copy staging (r19, unchanged).
// ---------------------------------------------------------------------------
__global__ __launch_bounds__(256) void k_context_mfma(
    const unsigned short* __restrict__ attnBf,
    const unsigned short* __restrict__ valT, float* __restrict__ ctx) {
  __shared__ __align__(16) char At[64 * 128];  // [m][k] bf16 swizzled, 8KB
  __shared__ __align__(16) char Bt[32 * 128];  // [n][k] bf16 swizzled, 4KB

  const int t = threadIdx.x;
  const int b = blockIdx.z;
  const int m0 = blockIdx.y * 64, n0 = blockIdx.x * 32;
  const int w = t >> 6, l = t & 63;
  const int wr = w >> 1, wc = w & 1;

  f32x4v acc[2];
  acc[0] = 0;
  acc[1] = 0;

  const int sr = t >> 2;        // A staging row 0..63
  const int sg = (t & 3);       // A granule base (2 granules/thread)
  const int sswz = sr & 7;
  const int rbs = t >> 3;       // B staging row 0..31
  const int gbs = t & 7;        // B granule

  for (int k0 = 0; k0 < 512; k0 += 64) {
    if (k0) __syncthreads();
    {  // stage A: pure bf16 copy, 2 x uint4 per thread
      const unsigned short* srca = &attnBf[(b * 512 + m0 + sr) * 512 + k0];
      char* dst = At + sr * 128;
#pragma unroll
      for (int h = 0; h < 2; ++h) {
        int g = sg * 2 + h;
        uint4 va = *(const uint4*)(srca + g * 8);
        *(uint4*)(dst + ((g ^ sswz) << 4)) = va;
      }
      // stage B^T: 32 rows x 8 granules, one uint4 per thread
      uint4 vb = *(const uint4*)&valT[(b * 512 + n0 + rbs) * 512 + k0 + gbs * 8];
      *(uint4*)(Bt + rbs * 128 + ((gbs ^ (rbs & 7)) << 4)) = vb;
    }
    __syncthreads();
#pragma unroll
    for (int ks = 0; ks < 2; ++ks) {
      const int gb = ks * 4 + (l >> 4);
      const int rb = wc * 16 + (l & 15);
      short8 bf_ = *(const short8*)(Bt + rb * 128 + ((gb ^ (rb & 7)) << 4));
#pragma unroll
      for (int mi = 0; mi < 2; ++mi) {
        int ra = wr * 32 + mi * 16 + (l & 15);
        short8 af = *(const short8*)(At + ra * 128 + ((gb ^ (ra & 7)) << 4));
        acc[mi] = __builtin_amdgcn_mfma_f32_16x16x32_bf16(af, bf_, acc[mi], 0, 0, 0);
      }
    }
  }
  __syncthreads();
#pragma unroll
  for (int mi = 0; mi < 2; ++mi) {
    int col = n0 + wc * 16 + (l & 15);
#pragma unroll
    for (int j = 0; j < 4; ++j) {
      int row = m0 + wr * 32 + mi * 16 + (l >> 4) * 4 + j;
      ctx[(b * 512 + row) * 512 + col] = acc[mi][j];
    }
  }
}

extern "C" void kernel_launch(void* const* d_in, const int* in_sizes, int n_in,
                              void* d_out, int out_size, void* d_ws, size_t ws_size,
                              hipStream_t stream) {
  const float* query = (const float*)d_in[0];
  const float* key   = (const float*)d_in[1];
  const float* value = (const float*)d_in[2];
  const float* w1    = (const float*)d_in[3];
  const float* w2    = (const float*)d_in[4];
  const float* v     = (const float*)d_in[5];

  float* attn = (float*)d_out;
  float* ctx  = attn + 8 * 512 * 512;

  float* Aexp = (float*)d_ws;                                    // 2MB
  unsigned short* BexpT = (unsigned short*)(Aexp + 4096 * 128);  // 1MB
  unsigned short* valT = BexpT + 128 * 4096;                     // 4MB
  unsigned short* attnBf = valT + 8 * 512 * 512;                 // 4MB (11MB tot)

  k_pre<<<dim3(512, 2), 256, 0, stream>>>(query, key, w1, w2, value,
                                          Aexp, BexpT, valT);
  k_score_softmax<<<dim3(64, 8), 512, 0, stream>>>(Aexp, BexpT, v, attn, attnBf);
  k_context_mfma<<<dim3(16, 8, 8), 256, 0, stream>>>(attnBf, valT, ctx);
}